// Round 1
// baseline (249.746 us; speedup 1.0000x reference)
//
#include <hip/hip_runtime.h>

// Problem constants
constexpr int BATCH = 4;
constexpr int SEQQ  = 1024;
constexpr int SEQK  = 2048;
constexpr int DIM   = 1024;
constexpr int NH    = 16;
constexpr int DH    = 64;
constexpr int RQ    = BATCH * SEQQ;          // 4096 q rows
constexpr int RK    = BATCH * SEQK;          // 8192 k rows (== v rows)
constexpr int RTOT  = RQ + 2 * RK;           // 20480
constexpr int BH    = BATCH * NH;            // 64
constexpr int NSLC  = 8;                     // s_kernel K-slices
constexpr float LN_EPS = 1e-5f;

typedef _Float16 f16;
typedef __attribute__((ext_vector_type(8))) _Float16 f16x8;
typedef __attribute__((ext_vector_type(4))) float f32x4;

__device__ __forceinline__ void async16(const void* g, void* l) {
  __builtin_amdgcn_global_load_lds(
      (const __attribute__((address_space(1))) void*)g,
      (__attribute__((address_space(3))) void*)l, 16, 0, 0);
}

// ---------------------------------------------------------------------------
// K0: fused LayerNorm -> fp16. One wave per row (no LDS, no barriers).
// ---------------------------------------------------------------------------
__global__ void __launch_bounds__(256) ln_to_f16(
    const float* __restrict__ q, const float* __restrict__ k,
    const float* __restrict__ v, const float* __restrict__ gamma,
    const float* __restrict__ beta, f16* __restrict__ a_h) {
  const int row = blockIdx.x * 4 + (threadIdx.x >> 6);
  const int lane = threadIdx.x & 63;
  const float* src;
  if (row < RQ)            src = q + (size_t)row * DIM;
  else if (row < RQ + RK)  src = k + (size_t)(row - RQ) * DIM;
  else                     src = v + (size_t)(row - RQ - RK) * DIM;
  float4 x[4];
  float s = 0.f, s2 = 0.f;
#pragma unroll
  for (int c = 0; c < 4; c++) {
    x[c] = ((const float4*)src)[c * 64 + lane];
    s  += x[c].x + x[c].y + x[c].z + x[c].w;
    s2 += x[c].x * x[c].x + x[c].y * x[c].y + x[c].z * x[c].z + x[c].w * x[c].w;
  }
#pragma unroll
  for (int off = 1; off < 64; off <<= 1) {
    s  += __shfl_xor(s, off);
    s2 += __shfl_xor(s2, off);
  }
  const float mu = s / DIM;
  const float rs = rsqrtf(s2 / DIM - mu * mu + LN_EPS);
#pragma unroll
  for (int c = 0; c < 4; c++) {
    float4 g = ((const float4*)gamma)[c * 64 + lane];
    float4 b = ((const float4*)beta)[c * 64 + lane];
    union { f16 h[4]; uint2 u; } o;
    o.h[0] = (f16)((x[c].x - mu) * rs * g.x + b.x);
    o.h[1] = (f16)((x[c].y - mu) * rs * g.y + b.y);
    o.h[2] = (f16)((x[c].z - mu) * rs * g.z + b.z);
    o.h[3] = (f16)((x[c].w - mu) * rs * g.w + b.w);
    ((uint2*)(a_h + (size_t)row * DIM))[c * 64 + lane] = o.u;
  }
}

// ---------------------------------------------------------------------------
// K0b: transpose + fp16 convert of W_in and W_out (1024x1024 each).
// ---------------------------------------------------------------------------
__global__ void __launch_bounds__(256) transpose_f16(
    const float* __restrict__ W0, const float* __restrict__ W1,
    f16* __restrict__ T0, f16* __restrict__ T1) {
  const float* W = blockIdx.z ? W1 : W0;
  f16* T = blockIdx.z ? T1 : T0;
  __shared__ float tile[32][33];
  int tx = threadIdx.x & 31, ty = threadIdx.x >> 5;
  int k0 = blockIdx.x * 32, n0 = blockIdx.y * 32;
#pragma unroll
  for (int i = 0; i < 4; i++)
    tile[ty + 8 * i][tx] = W[(size_t)(k0 + ty + 8 * i) * DIM + n0 + tx];
  __syncthreads();
#pragma unroll
  for (int i = 0; i < 4; i++)
    T[(size_t)(n0 + ty + 8 * i) * DIM + k0 + tx] = (f16)tile[tx][ty + 8 * i];
}

// ---------------------------------------------------------------------------
// K1: projection GEMM, 256x256 tile, 8-phase pipelined schedule.
//   f[RTOT x 1024] = a_h[RTOT x 1024] @ wt_in^T, q/k rows pre-normalized
//   per head (each wave's 64-col span is exactly one head).
//
// Structure (T2+T3+T4+T5):
//   - 8 waves (2M x 4N), per-wave 128x64 output, acc[8][4] f32x4.
//   - LDS 128 KiB: per operand 2 tile-buffers x 2 K-halves x (256 rows x 32 K).
//     A K-half (16 KB) is the contiguous staging unit (2 global_load_lds x 16B
//     per thread per stage).
//   - Phase order per K-tile: (mh,ks) = (0,0),(1,0),(0,1),(1,1); B-fragments
//     reused in registers across the two mh phases.
//   - Each phase stages exactly one K-half; s_waitcnt vmcnt(8) (= 4 stages
//     in flight, never 0) per phase; raw s_barrier (no vmcnt(0) drain).
//   - Slot-XOR swizzle ((lane>>4)^((lane>>1)&3)) applied identically to the
//     staging SOURCE address and the ds_read address -> 2-way conflicts (free).
//
// Race-freedom of stage placement (verified by phase-window analysis):
//   P1:A(t1,K1) P2:B(t1,K1) P3:A(t2,K0) P4:B(t2,K0)
//   P5:A(t2,K1) P6:B(t2,K1) P7:A(t3,K0) P8:B(t3,K0)
//   Every staged slot's last LDS read completes >=1 end-barrier before the
//   stage issue; every read's data is covered by a vmcnt(8)+barrier >=4
//   stages after its issue.
// ---------------------------------------------------------------------------
constexpr int NT_K = DIM / 64;   // 16 K-tiles
constexpr int NI_K = NT_K / 2;   // 8 iterations (2 K-tiles each)

#define STAGE(P, gp, kt, BUFC, h)                                         \
  do {                                                                    \
    if ((kt) < NT_K) {                                                    \
      f16* dst_ = (P) + ((BUFC) * 2 + (h)) * 8192 + lbase;                \
      const f16* s0_ = (gp) + (kt) * 64 + (h) * 32;                       \
      async16(s0_, dst_);                                                 \
      async16(s0_ + (size_t)128 * DIM, dst_ + 128 * 32);                  \
    }                                                                     \
  } while (0)

#define PHASE(PB, PK, PM, READB, SP, SG, skt, sbuf, sh)                   \
  {                                                                       \
    _Pragma("unroll") for (int f_ = 0; f_ < 4; ++f_)                      \
      af[f_] = *(const f16x8*)(aBase + ((PB)*2 + (PK)) * 8192 +           \
                               ((PM)*64 + f_*16) * 32);                   \
    if (READB) {                                                          \
      _Pragma("unroll") for (int j_ = 0; j_ < 4; ++j_)                    \
        bf[j_] = *(const f16x8*)(bBase + ((PB)*2 + (PK)) * 8192 +         \
                                 (j_*16) * 32);                           \
    }                                                                     \
    STAGE(SP, SG, skt, sbuf, sh);                                         \
    __builtin_amdgcn_sched_barrier(0);                                    \
    asm volatile("s_waitcnt vmcnt(8)" ::: "memory");                      \
    __builtin_amdgcn_s_barrier();                                         \
    __builtin_amdgcn_sched_barrier(0);                                    \
    asm volatile("s_waitcnt lgkmcnt(0)" ::: "memory");                    \
    __builtin_amdgcn_sched_barrier(0);                                    \
    __builtin_amdgcn_s_setprio(1);                                        \
    _Pragma("unroll") for (int f_ = 0; f_ < 4; ++f_)                      \
      _Pragma("unroll") for (int j_ = 0; j_ < 4; ++j_)                    \
        acc[(PM)*4 + f_][j_] = __builtin_amdgcn_mfma_f32_16x16x32_f16(    \
            af[f_], bf[j_], acc[(PM)*4 + f_][j_], 0, 0, 0);               \
    __builtin_amdgcn_s_setprio(0);                                        \
    __builtin_amdgcn_sched_barrier(0);                                    \
    __builtin_amdgcn_s_barrier();                                         \
  }

__global__ void __launch_bounds__(512, 2) proj_gemm(
    const f16* __restrict__ A, const f16* __restrict__ Bt,
    f16* __restrict__ C) {
  __shared__ __align__(16) f16 As[2 * 2 * 256 * 32];   // 64 KB
  __shared__ __align__(16) f16 Bs[2 * 2 * 256 * 32];   // 64 KB

  const int t = threadIdx.x;
  const int wid = t >> 6;
  const int lane = t & 63;
  const int la15 = lane & 15;

  // bijective XCD swizzle (320 % 8 == 0); col-tile fastest within an XCD
  // chunk so a row-panel's 4 column tiles share one XCD's L2.
  const int bid = blockIdx.x;
  const int swz = (bid & 7) * 40 + (bid >> 3);
  const int row0 = (swz >> 2) * 256;
  const int col0 = (swz & 3) * 256;

  const int wm = (wid >> 2) * 128;      // warp_m in {0,1}
  const int wn = (wid & 3) * 64;        // warp_n in {0..3}

  // staging: per-thread source offset (row = wid*16 + lane>>2, slot-XOR)
  const size_t goff = (size_t)(wid * 16 + (lane >> 2)) * DIM +
                      (((lane & 3) ^ ((lane >> 3) & 3)) * 8);
  const f16* gA = A + (size_t)row0 * DIM + goff;
  const f16* gB = Bt + (size_t)col0 * DIM + goff;
  const int lbase = (wid * 16) * 32;    // wave-uniform LDS base (f16 units)

  // fragment read bases: all phase offsets fold into ds_read immediates
  const int kslot = ((lane >> 4) ^ ((lane >> 1) & 3)) * 8;
  const f16* aBase = As + (wm + la15) * 32 + kslot;
  const f16* bBase = Bs + (wn + la15) * 32 + kslot;

  f32x4 acc[8][4];
#pragma unroll
  for (int i = 0; i < 8; i++)
#pragma unroll
    for (int j = 0; j < 4; j++) acc[i][j] = (f32x4){0.f, 0.f, 0.f, 0.f};
  f16x8 af[4], bf[4];

  // prologue: T0 both K-halves + T1 K-half0 (= steady-state P3..P8 pattern)
  STAGE(As, gA, 0, 0, 0); STAGE(Bs, gB, 0, 0, 0);
  STAGE(As, gA, 0, 0, 1); STAGE(Bs, gB, 0, 0, 1);
  STAGE(As, gA, 1, 1, 0); STAGE(Bs, gB, 1, 1, 0);
  __builtin_amdgcn_sched_barrier(0);
  asm volatile("s_waitcnt vmcnt(8)" ::: "memory");  // T0-K0 landed
  __builtin_amdgcn_s_barrier();
  __builtin_amdgcn_sched_barrier(0);

#pragma unroll 1
  for (int it = 0; it < NI_K; ++it) {
    const int t1 = 2 * it + 1, t2 = 2 * it + 2, t3 = 2 * it + 3;
    PHASE(0, 0, 0, 1, As, gA, t1, 1, 1)   // P1: compute T0(K0,mh0), stage A(t1,K1)
    PHASE(0, 0, 1, 0, Bs, gB, t1, 1, 1)   // P2: T0(K0,mh1),          B(t1,K1)
    PHASE(0, 1, 0, 1, As, gA, t2, 0, 0)   // P3: T0(K1,mh0),          A(t2,K0)
    PHASE(0, 1, 1, 0, Bs, gB, t2, 0, 0)   // P4: T0(K1,mh1),          B(t2,K0)
    PHASE(1, 0, 0, 1, As, gA, t2, 0, 1)   // P5: T1(K0,mh0),          A(t2,K1)
    PHASE(1, 0, 1, 0, Bs, gB, t2, 0, 1)   // P6: T1(K0,mh1),          B(t2,K1)
    PHASE(1, 1, 0, 1, As, gA, t3, 1, 0)   // P7: T1(K1,mh0),          A(t3,K0)
    PHASE(1, 1, 1, 0, Bs, gB, t3, 1, 0)   // P8: T1(K1,mh1),          B(t3,K0)
  }

  // per-head normalization for q/k rows (block-uniform: row0 multiple of 256)
  if (row0 < RQ + RK) {
#pragma unroll
    for (int m = 0; m < 8; ++m)
#pragma unroll
      for (int r = 0; r < 4; ++r) {
        float s = acc[m][0][r] * acc[m][0][r] + acc[m][1][r] * acc[m][1][r]
                + acc[m][2][r] * acc[m][2][r] + acc[m][3][r] * acc[m][3][r];
        s += __shfl_xor(s, 1);
        s += __shfl_xor(s, 2);
        s += __shfl_xor(s, 4);
        s += __shfl_xor(s, 8);
        const float inv = rsqrtf(s);
#pragma unroll
        for (int j = 0; j < 4; ++j) acc[m][j][r] *= inv;
      }
  }

  // epilogue: C/D layout col=lane&15, row=(lane>>4)*4+reg
  const int crow = (lane >> 4) * 4;
#pragma unroll
  for (int j = 0; j < 4; ++j) {
    const int col = col0 + wn + j * 16 + la15;
#pragma unroll
    for (int m = 0; m < 8; ++m) {
      f16* Cp = C + (size_t)(row0 + wm + m * 16 + crow) * DIM + col;
#pragma unroll
      for (int r = 0; r < 4; ++r) Cp[(size_t)r * DIM] = (f16)acc[m][j][r];
    }
  }
}

// ---------------------------------------------------------------------------
// MFMA fp16 GEMM (kept for the final GEMM, MT=64 path).
// ---------------------------------------------------------------------------
template <int MT, bool OUT_F16, bool NORMS, bool BIAS, bool PERB>
__global__ void __launch_bounds__(256) mfma_gemm(
    const f16* __restrict__ A, const f16* __restrict__ Bt,
    void* __restrict__ Cout, const float* __restrict__ bias) {
  constexpr int JT = (MT == 128) ? 4 : 2;
  __shared__ f16 Asl[2][MT * 32];
  __shared__ f16 Bsl[2][128 * 32];
  const int t = threadIdx.x;
  const int wid = t >> 6;
  const int lane = t & 63;
  const int row0 = blockIdx.x * MT;
  const int col0 = blockIdx.y * 128;
  const int wm = (MT == 128) ? (wid >> 1) * 64 : 0;
  const int wn = (MT == 128) ? (wid & 1) * 64 : wid * 32;

  const f16* BtB = PERB ? Bt + (size_t)(row0 >> 10) * DIM * DIM : Bt;

  const int rB = 32 * wid + (lane >> 2);
  const int qB = ((lane & 3) - ((rB >> 1) & 3)) & 3;
  const f16* gB = BtB + (size_t)(col0 + rB) * DIM + qB * 8;
  f16* lB0 = Bsl[0] + 32 * wid * 32;
  f16* lB1 = Bsl[1] + 32 * wid * 32;
  const int rA = (MT == 128 ? 32 : 16) * wid + (lane >> 2);
  const int qA = ((lane & 3) - ((rA >> 1) & 3)) & 3;
  const f16* gA = A + (size_t)(row0 + rA) * DIM + qA * 8;
  f16* lA0 = Asl[0] + (MT == 128 ? 32 : 16) * wid * 32;
  f16* lA1 = Asl[1] + (MT == 128 ? 32 : 16) * wid * 32;

  f32x4 acc[4][JT];
#pragma unroll
  for (int i = 0; i < 4; i++)
#pragma unroll
    for (int j = 0; j < JT; j++) acc[i][j] = (f32x4){0.f, 0.f, 0.f, 0.f};

  const int mrow = lane & 15;
  const int kq_p = (((lane >> 4) + ((lane >> 1) & 3)) & 3) * 8;

  for (int kt = 0; kt < DIM / 64; ++kt) {
    if (kt) __syncthreads();
    const int ko = kt * 64;
    async16(gA + ko,      lA0);
    if (MT == 128) async16(gA + ko + 16 * DIM, lA0 + 512);
    async16(gB + ko,      lB0);
    async16(gB + ko + 16 * DIM, lB0 + 512);
    async16(gA + ko + 32, lA1);
    if (MT == 128) async16(gA + ko + 32 + 16 * DIM, lA1 + 512);
    async16(gB + ko + 32, lB1);
    async16(gB + ko + 32 + 16 * DIM, lB1 + 512);
    __syncthreads();

#pragma unroll
    for (int h = 0; h < 2; ++h) {
      f16x8 af[4], bf[JT];
#pragma unroll
      for (int i = 0; i < 4; i++)
        af[i] = *(const f16x8*)(Asl[h] + (wm + i * 16 + mrow) * 32 + kq_p);
#pragma unroll
      for (int j = 0; j < JT; j++)
        bf[j] = *(const f16x8*)(Bsl[h] + (wn + j * 16 + mrow) * 32 + kq_p);
#pragma unroll
      for (int i = 0; i < 4; i++)
#pragma unroll
        for (int j = 0; j < JT; j++)
          acc[i][j] = __builtin_amdgcn_mfma_f32_16x16x32_f16(af[i], bf[j], acc[i][j], 0, 0, 0);
    }
  }

  if (NORMS && MT == 128) {
    if (row0 < RQ + RK) {
      float sums[4][4];
#pragma unroll
      for (int i = 0; i < 4; i++)
#pragma unroll
        for (int r = 0; r < 4; r++) {
          float s = 0.f;
#pragma unroll
          for (int j = 0; j < JT; j++) s += acc[i][j][r] * acc[i][j][r];
          sums[i][r] = s;
        }
#pragma unroll
      for (int off = 1; off < 16; off <<= 1)
#pragma unroll
        for (int i = 0; i < 4; i++)
#pragma unroll
          for (int r = 0; r < 4; r++)
            sums[i][r] += __shfl_xor(sums[i][r], off);
#pragma unroll
      for (int i = 0; i < 4; i++)
#pragma unroll
        for (int r = 0; r < 4; r++) {
          const float inv = rsqrtf(sums[i][r]);
#pragma unroll
          for (int j = 0; j < JT; j++) acc[i][j][r] *= inv;
        }
    }
  }

  const int ccol = lane & 15;
  const int crow = (lane >> 4) * 4;
  if (OUT_F16) {
    f16* C = (f16*)Cout;
#pragma unroll
    for (int j = 0; j < JT; j++) {
      const int col = col0 + wn + j * 16 + ccol;
#pragma unroll
      for (int i = 0; i < 4; i++) {
        f16* Cp = C + (size_t)(row0 + wm + i * 16 + crow) * DIM + col;
#pragma unroll
        for (int r = 0; r < 4; r++) Cp[(size_t)r * DIM] = (f16)acc[i][j][r];
      }
    }
  } else {
    float* C = (float*)Cout;
#pragma unroll
    for (int j = 0; j < JT; j++) {
      const int col = col0 + wn + j * 16 + ccol;
      float bv = BIAS ? bias[col] : 0.f;
#pragma unroll
      for (int i = 0; i < 4; i++) {
        float* Cp = C + (size_t)(row0 + wm + i * 16 + crow) * DIM + col;
#pragma unroll
        for (int r = 0; r < 4; r++) Cp[(size_t)r * DIM] = acc[i][j][r] + bv;
      }
    }
  }
}

// ---------------------------------------------------------------------------
// K3: per-(slice,b,h) partial S = sum over 256 m of g_k[m] outer f_v[m].
// ---------------------------------------------------------------------------
__global__ void __launch_bounds__(256) s_kernel(
    const f16* __restrict__ f, float* __restrict__ S4) {
  const int bh = blockIdx.x;
  const int b = bh >> 4, h = bh & 15;
  const int mbase = blockIdx.y * (SEQK / NSLC);
  const int t = threadIdx.x;
  __shared__ float ks[32][68];
  __shared__ float vs[32][68];
  const int lm   = t >> 3;
  const int lseg = (t & 7) * 8;
  const int d1 = (t & 15) * 4;
  const int d2 = (t >> 4) * 4;
  float acc[4][4] = {{0.f}};
  const f16* fk_base = f + ((size_t)RQ + (size_t)b * SEQK) * DIM + h * DH;
  const f16* fv_base = f + ((size_t)RQ + RK + (size_t)b * SEQK) * DIM + h * DH;

  int m = mbase + lm;
  f16x8 kv = *(const f16x8*)(fk_base + (size_t)m * DIM + lseg);
  f16x8 vv = *(const f16x8*)(fv_base + (size_t)m * DIM + lseg);

  constexpr int SUBS = SEQK / NSLC / 32;  // 8
  for (int sub = 0; sub < SUBS; ++sub) {
    __syncthreads();
#pragma unroll
    for (int e = 0; e < 8; e++) {
      ks[lm][lseg + e] = (float)kv[e];
      vs[lm][lseg + e] = (float)vv[e];
    }
    __syncthreads();
    if (sub + 1 < SUBS) {
      m = mbase + (sub + 1) * 32 + lm;
      kv = *(const f16x8*)(fk_base + (size_t)m * DIM + lseg);
      vv = *(const f16x8*)(fv_base + (size_t)m * DIM + lseg);
    }
#pragma unroll
    for (int mm = 0; mm < 32; ++mm) {
      float4 kk = *(const float4*)&ks[mm][d1];
      float4 vv2 = *(const float4*)&vs[mm][d2];
      acc[0][0] = fmaf(kk.x, vv2.x, acc[0][0]);
      acc[0][1] = fmaf(kk.x, vv2.y, acc[0][1]);
      acc[0][2] = fmaf(kk.x, vv2.z, acc[0][2]);
      acc[0][3] = fmaf(kk.x, vv2.w, acc[0][3]);
      acc[1][0] = fmaf(kk.y, vv2.x, acc[1][0]);
      acc[1][1] = fmaf(kk.y, vv2.y, acc[1][1]);
      acc[1][2] = fmaf(kk.y, vv2.z, acc[1][2]);
      acc[1][3] = fmaf(kk.y, vv2.w, acc[1][3]);
      acc[2][0] = fmaf(kk.z, vv2.x, acc[2][0]);
      acc[2][1] = fmaf(kk.z, vv2.y, acc[2][1]);
      acc[2][2] = fmaf(kk.z, vv2.z, acc[2][2]);
      acc[2][3] = fmaf(kk.z, vv2.w, acc[2][3]);
      acc[3][0] = fmaf(kk.w, vv2.x, acc[3][0]);
      acc[3][1] = fmaf(kk.w, vv2.y, acc[3][1]);
      acc[3][2] = fmaf(kk.w, vv2.z, acc[3][2]);
      acc[3][3] = fmaf(kk.w, vv2.w, acc[3][3]);
    }
  }
  float* Sp = S4 + ((size_t)blockIdx.y * BH + bh) * DH * DH;
#pragma unroll
  for (int i = 0; i < 4; i++)
#pragma unroll
    for (int j = 0; j < 4; j++)
      Sp[(d1 + i) * DH + (d2 + j)] = acc[i][j];
}

// ---------------------------------------------------------------------------
// K3b: sum the NSLC partial S slices -> Sh fp16 [bh][d1][d2] row-major.
// ---------------------------------------------------------------------------
__global__ void __launch_bounds__(256) s_reduce(
    const float* __restrict__ S4, f16* __restrict__ Sh) {
  const int bh = blockIdx.x;
  const int t = threadIdx.x;
  const size_t base = (size_t)bh * DH * DH + t * 16;
  constexpr size_t STR = (size_t)BH * DH * DH;
#pragma unroll
  for (int c = 0; c < 4; c++) {
    float4 s = {0.f, 0.f, 0.f, 0.f};
#pragma unroll
    for (int p = 0; p < NSLC; p++) {
      float4 sp = *(const float4*)(S4 + base + p * STR + 4 * c);
      s.x += sp.x; s.y += sp.y; s.z += sp.z; s.w += sp.w;
    }
    union { f16 h[4]; uint2 u; } o;
    o.h[0] = (f16)s.x; o.h[1] = (f16)s.y; o.h[2] = (f16)s.z; o.h[3] = (f16)s.w;
    *(uint2*)(Sh + base + 4 * c) = o.u;
  }
}

// ---------------------------------------------------------------------------
// K3c: Mt[b][n][64h+d1] = sum_d2 wt_out[n][64h+d2] * Sh[b,h][d1][d2]
// ---------------------------------------------------------------------------
__global__ void __launch_bounds__(256) m_build(
    const f16* __restrict__ wt_out, const f16* __restrict__ Sh,
    f16* __restrict__ Mt) {
  const int n0 = blockIdx.x * 128;
  const int bh = blockIdx.y;
  const int b = bh >> 4, h = bh & 15;
  __shared__ f16 Asl[128 * 64];
  __shared__ f16 Bsl[64 * 64];
  const int t = threadIdx.x;
  const int wid = t >> 6, lane = t & 63;

  const f16* gA = wt_out + (size_t)(n0 + 32 * wid + (lane >> 3)) * DIM
                  + 64 * h + (lane & 7) * 8;
  f16* lA = Asl + 32 * wid * 64;
  const f16* gB = Sh + (size_t)bh * DH * DH + (16 * wid + (lane >> 3)) * 64
                  + (lane & 7) * 8;
  f16* lB = Bsl + 16 * wid * 64;
#pragma unroll
  for (int o = 0; o < 4; o++) async16(gA + (size_t)(8 * o) * DIM, lA + 8 * o * 64);
  async16(gB, lB);
  async16(gB + 8 * 64, lB + 8 * 64);
  __syncthreads();

  const int wm = (wid >> 1) * 64;
  const int wn = (wid & 1) * 32;
  const int mrow = lane & 15;
  f32x4 acc[4][2];
#pragma unroll
  for (int i = 0; i < 4; i++)
#pragma unroll
    for (int j = 0; j < 2; j++) acc[i][j] = (f32x4){0.f, 0.f, 0.f, 0.f};

#pragma unroll
  for (int kh = 0; kh < 2; kh++) {
    const int kq = kh * 32 + (lane >> 4) * 8;
    f16x8 af[4], bf[2];
#pragma unroll
    for (int i = 0; i < 4; i++)
      af[i] = *(const f16x8*)(Asl + (wm + i * 16 + mrow) * 64 + kq);
#pragma unroll
    for (int j = 0; j < 2; j++)
      bf[j] = *(const f16x8*)(Bsl + (wn + j * 16 + mrow) * 64 + kq);
#pragma unroll
    for (int i = 0; i < 4; i++)
#pragma unroll
      for (int j = 0; j < 2; j++)
        acc[i][j] = __builtin_amdgcn_mfma_f32_16x16x32_f16(af[i], bf[j], acc[i][j], 0, 0, 0);
  }

  const int ccol = lane & 15;
  const int crow = (lane >> 4) * 4;
  f16* Mb = Mt + (size_t)b * DIM * DIM;
#pragma unroll
  for (int j = 0; j < 2; j++) {
    const int col = 64 * h + wn + j * 16 + ccol;
#pragma unroll
    for (int i = 0; i < 4; i++) {
      f16* Mp = Mb + (size_t)(n0 + wm + i * 16 + crow) * DIM + col;
#pragma unroll
      for (int r = 0; r < 4; r++) Mp[(size_t)r * DIM] = (f16)acc[i][j][r];
    }
  }
}

// ---------------------------------------------------------------------------
extern "C" void kernel_launch(void* const* d_in, const int* in_sizes, int n_in,
                              void* d_out, int out_size, void* d_ws, size_t ws_size,
                              hipStream_t stream) {
  const float* q     = (const float*)d_in[0];
  const float* k     = (const float*)d_in[1];
  const float* v     = (const float*)d_in[2];
  const float* gamma = (const float*)d_in[3];
  const float* beta  = (const float*)d_in[4];
  const float* W_in  = (const float*)d_in[5];
  const float* W_out = (const float*)d_in[6];
  const float* b_out = (const float*)d_in[7];
  float* out = (float*)d_out;

  // workspace layout
  char* w = (char*)d_ws;
  f16*   f      = (f16*)w;                                     // 40 MB
  f16*   a_h    = f + (size_t)RTOT * DIM;                      // 40 MB
  f16*   wt_in  = a_h + (size_t)RTOT * DIM;                    // 2 MB
  f16*   wt_out = wt_in + (size_t)DIM * DIM;                   // 2 MB
  f16*   Mt     = wt_out + (size_t)DIM * DIM;                  // 8 MB
  f16*   Sh     = Mt + (size_t)BATCH * DIM * DIM;              // 512 KB
  float* S4     = (float*)(Sh + (size_t)BH * DH * DH);         // 8 MB

  ln_to_f16<<<RTOT / 4, 256, 0, stream>>>(q, k, v, gamma, beta, a_h);
  transpose_f16<<<dim3(DIM / 32, DIM / 32, 2), 256, 0, stream>>>(
      W_in, W_out, wt_in, wt_out);

  // f = LN(t) @ W_in for all rows; q/k rows pre-normalized per head
  proj_gemm<<<dim3((RTOT / 256) * (DIM / 256)), 512, 0, stream>>>(a_h, wt_in, f);

  s_kernel<<<dim3(BH, NSLC), 256, 0, stream>>>(f, S4);

  s_reduce<<<BH, 256, 0, stream>>>(S4, Sh);

  m_build<<<dim3(DIM / 128, BH), 256, 0, stream>>>(wt_out, Sh, Mt);

  // out = g_q @ Mt[b]^T + b_out (per-batch weights)
  mfma_gemm<64, false, false, true, true>
      <<<dim3(RQ / 64, DIM / 128), 256, 0, stream>>>(f, Mt, out, b_out);
}

// Round 2
// 238.906 us; speedup vs baseline: 1.0454x; 1.0454x over previous
//
#include <hip/hip_runtime.h>

// Problem constants
constexpr int BATCH = 4;
constexpr int SEQQ  = 1024;
constexpr int SEQK  = 2048;
constexpr int DIM   = 1024;
constexpr int NH    = 16;
constexpr int DH    = 64;
constexpr int RQ    = BATCH * SEQQ;          // 4096 q rows
constexpr int RK    = BATCH * SEQK;          // 8192 k rows (== v rows)
constexpr int RTOT  = RQ + 2 * RK;           // 20480
constexpr int BH    = BATCH * NH;            // 64
constexpr int NSLC  = 8;                     // s_kernel K-slices
constexpr float LN_EPS = 1e-5f;

typedef _Float16 f16;
typedef __attribute__((ext_vector_type(8))) _Float16 f16x8;
typedef __attribute__((ext_vector_type(4))) float f32x4;

__device__ __forceinline__ void async16(const void* g, void* l) {
  __builtin_amdgcn_global_load_lds(
      (const __attribute__((address_space(1))) void*)g,
      (__attribute__((address_space(3))) void*)l, 16, 0, 0);
}

// ---------------------------------------------------------------------------
// K0: fused LayerNorm -> fp16. One wave per row (no LDS, no barriers).
// ---------------------------------------------------------------------------
__global__ void __launch_bounds__(256) ln_to_f16(
    const float* __restrict__ q, const float* __restrict__ k,
    const float* __restrict__ v, const float* __restrict__ gamma,
    const float* __restrict__ beta, f16* __restrict__ a_h) {
  const int row = blockIdx.x * 4 + (threadIdx.x >> 6);
  const int lane = threadIdx.x & 63;
  const float* src;
  if (row < RQ)            src = q + (size_t)row * DIM;
  else if (row < RQ + RK)  src = k + (size_t)(row - RQ) * DIM;
  else                     src = v + (size_t)(row - RQ - RK) * DIM;
  float4 x[4];
  float s = 0.f, s2 = 0.f;
#pragma unroll
  for (int c = 0; c < 4; c++) {
    x[c] = ((const float4*)src)[c * 64 + lane];
    s  += x[c].x + x[c].y + x[c].z + x[c].w;
    s2 += x[c].x * x[c].x + x[c].y * x[c].y + x[c].z * x[c].z + x[c].w * x[c].w;
  }
#pragma unroll
  for (int off = 1; off < 64; off <<= 1) {
    s  += __shfl_xor(s, off);
    s2 += __shfl_xor(s2, off);
  }
  const float mu = s / DIM;
  const float rs = rsqrtf(s2 / DIM - mu * mu + LN_EPS);
#pragma unroll
  for (int c = 0; c < 4; c++) {
    float4 g = ((const float4*)gamma)[c * 64 + lane];
    float4 b = ((const float4*)beta)[c * 64 + lane];
    union { f16 h[4]; uint2 u; } o;
    o.h[0] = (f16)((x[c].x - mu) * rs * g.x + b.x);
    o.h[1] = (f16)((x[c].y - mu) * rs * g.y + b.y);
    o.h[2] = (f16)((x[c].z - mu) * rs * g.z + b.z);
    o.h[3] = (f16)((x[c].w - mu) * rs * g.w + b.w);
    ((uint2*)(a_h + (size_t)row * DIM))[c * 64 + lane] = o.u;
  }
}

// ---------------------------------------------------------------------------
// K0b: transpose + fp16 convert of W_in and W_out (1024x1024 each).
// ---------------------------------------------------------------------------
__global__ void __launch_bounds__(256) transpose_f16(
    const float* __restrict__ W0, const float* __restrict__ W1,
    f16* __restrict__ T0, f16* __restrict__ T1) {
  const float* W = blockIdx.z ? W1 : W0;
  f16* T = blockIdx.z ? T1 : T0;
  __shared__ float tile[32][33];
  int tx = threadIdx.x & 31, ty = threadIdx.x >> 5;
  int k0 = blockIdx.x * 32, n0 = blockIdx.y * 32;
#pragma unroll
  for (int i = 0; i < 4; i++)
    tile[ty + 8 * i][tx] = W[(size_t)(k0 + ty + 8 * i) * DIM + n0 + tx];
  __syncthreads();
#pragma unroll
  for (int i = 0; i < 4; i++)
    T[(size_t)(n0 + ty + 8 * i) * DIM + k0 + tx] = (f16)tile[tx][ty + 8 * i];
}

// ---------------------------------------------------------------------------
// K1: projection GEMM, 320x256 tile -> grid 64x4 = 256 blocks = 1 per CU
//     (one dispatch round, no tail). 8-phase pipelined schedule.
//
//   f[RTOT x 1024] = a_h[RTOT x 1024] @ wt_in^T; q/k rows (global row <
//   RQ+RK) pre-normalized per head (wave's 64-col span = one head).
//
// Geometry: 8 waves (2M x 4N); per-wave 160x64 out, acc[10][4] f32x4.
// LDS 144 KiB: A 2 tile-bufs x [320 rows][64 K], B 2 x [256][64], f16.
// Chunk swizzle: within a row, 16B chunk c' = (half*4+slot) ^ (row&7),
// applied to BOTH the staging source address and the ds_read address
// -> 2 lanes/bank on reads (free); staging dest stays linear
// (global_load_lds requirement).
//
// Stage events (full K-tile, uniform loads): A-tile = 5 async16/thread,
// B-tile = 4. Placement & waits per iteration (2 K-tiles: Te=2it even in
// buf0, To=2it+1 odd in buf1), phases P1..P8 = (buf,half,mh):
//   P1 (0,K0,mh0): stage A(2it+1)->buf1; vmcnt(5)  [drains prev P5+P6 = 9]
//   P2 (0,K0,mh1): stage B(2it+1)->buf1
//   P3 (0,K1,mh0)  P4 (0,K1,mh1)
//   P5 (1,K0,mh0): stage A(2it+2)->buf0; vmcnt(5)  [drains P1+P2 = 9]
//   P6 (1,K0,mh1): stage B(2it+2)->buf0
//   P7 (1,K1,mh0)  P8 (1,K1,mh1)
// Overwrite safety: each stage targets a buffer whose last ds_read was
// >=1 end-of-phase barrier earlier. Last iteration peeled (no P5/P6
// stages; P5 uses vmcnt(0)). bf reused in registers across mh phases.
// ---------------------------------------------------------------------------
constexpr int PT_A = 320 * 64;   // f16 per A tile buffer (20480)
constexpr int PT_B = 256 * 64;   // f16 per B tile buffer (16384)

#define STAGE_A(buf, kt) do {                                        \
    const f16* s_ = gA + (size_t)(kt) * 64;                          \
    f16* d_ = AsW + (buf) * PT_A;                                    \
    async16(s_,          d_);                                        \
    async16(s_ +  65536, d_ + 4096);                                 \
    async16(s_ + 131072, d_ + 8192);                                 \
    async16(s_ + 196608, d_ + 12288);                                \
    async16(s_ + 262144, d_ + 16384);                                \
  } while (0)

#define STAGE_B(buf, kt) do {                                        \
    const f16* s_ = gB + (size_t)(kt) * 64;                          \
    f16* d_ = BsW + (buf) * PT_B;                                    \
    async16(s_,          d_);                                        \
    async16(s_ +  65536, d_ + 4096);                                 \
    async16(s_ + 131072, d_ + 8192);                                 \
    async16(s_ + 196608, d_ + 12288);                                \
  } while (0)

#define WT5 asm volatile("s_waitcnt vmcnt(5)" ::: "memory")
#define WT0 asm volatile("s_waitcnt vmcnt(0)" ::: "memory")
#define WTN ((void)0)
#define STN ((void)0)

#define PH(BUF, H, MH, RB, STG, WT) {                                \
    STG;                                                             \
    __builtin_amdgcn_sched_barrier(0);                               \
    WT;                                                              \
    __builtin_amdgcn_s_barrier();                                    \
    __builtin_amdgcn_sched_barrier(0);                               \
    if (RB) {                                                        \
      _Pragma("unroll") for (int j_ = 0; j_ < 4; ++j_)               \
        bf[j_] = *(const f16x8*)(bB##H + (BUF) * PT_B + j_ * 1024);  \
    }                                                                \
    _Pragma("unroll") for (int f_ = 0; f_ < 5; ++f_)                 \
      af[f_] = *(const f16x8*)(aB##H + (BUF) * PT_A + (MH) * 5120 +  \
                               f_ * 1024);                           \
    __builtin_amdgcn_s_setprio(1);                                   \
    _Pragma("unroll") for (int f_ = 0; f_ < 5; ++f_)                 \
      _Pragma("unroll") for (int j_ = 0; j_ < 4; ++j_)               \
        acc[(MH) * 5 + f_][j_] = __builtin_amdgcn_mfma_f32_16x16x32_f16( \
            af[f_], bf[j_], acc[(MH) * 5 + f_][j_], 0, 0, 0);        \
    __builtin_amdgcn_s_setprio(0);                                   \
    __builtin_amdgcn_sched_barrier(0);                               \
    __builtin_amdgcn_s_barrier();                                    \
  }

__global__ void __launch_bounds__(512, 2) proj_gemm(
    const f16* __restrict__ A, const f16* __restrict__ Bt,
    f16* __restrict__ C) {
  __shared__ __align__(16) f16 As[2 * PT_A];   // 80 KB
  __shared__ __align__(16) f16 Bs[2 * PT_B];   // 64 KB

  const int tid = threadIdx.x;
  const int wid = tid >> 6;
  const int lane = tid & 63;
  const int la15 = lane & 15;

  // bijective XCD swizzle (256 % 8 == 0); col-tile fastest within an XCD
  // chunk so a row-panel's 4 column tiles share one XCD's L2.
  const int bid = blockIdx.x;
  const int swz = (bid & 7) * 32 + (bid >> 3);
  const int row0 = (swz >> 2) * 320;
  const int col0 = (swz & 3) * 256;

  const int wm = (wid >> 2) * 160;      // warp_m in {0,1}
  const int wn = (wid & 3) * 64;        // warp_n in {0..3}

  // ---- staging source (per-thread), chunk-XOR pre-applied to source ----
  // LDS chunk o = i*512 + tid -> row = i*64 + (tid>>3), c' = tid&7;
  // logical (half,slot): h*4+s = c' ^ (row&7) = (tid&7) ^ ((tid>>3)&7).
  const int hs = (tid & 7) ^ ((tid >> 3) & 7);
  const f16* gA = A + (size_t)(row0 + (tid >> 3)) * DIM + (hs >> 2) * 32 +
                  (hs & 3) * 8;
  const f16* gB = Bt + (size_t)(col0 + (tid >> 3)) * DIM + (hs >> 2) * 32 +
                  (hs & 3) * 8;
  f16* AsW = As + wid * 512;            // wave-uniform LDS dest bases
  f16* BsW = Bs + wid * 512;

  // ---- fragment read bases (per half), XOR folded per-thread ----
  const int g = lane >> 4;
  const int r7 = la15 & 7;
  const int cs0 = (g ^ r7) * 8;             // half 0 chunk
  const int cs1 = ((4 + g) ^ r7) * 8;       // half 1 chunk
  const f16* aB0 = As + (wm + la15) * 64 + cs0;
  const f16* aB1 = As + (wm + la15) * 64 + cs1;
  const f16* bB0 = Bs + (wn + la15) * 64 + cs0;
  const f16* bB1 = Bs + (wn + la15) * 64 + cs1;

  f32x4 acc[10][4];
#pragma unroll
  for (int i = 0; i < 10; i++)
#pragma unroll
    for (int j = 0; j < 4; j++) acc[i][j] = (f32x4){0.f, 0.f, 0.f, 0.f};
  f16x8 af[5], bf[4];

  // prologue: tile 0 into buf0, drain fully
  STAGE_A(0, 0);
  STAGE_B(0, 0);
  __builtin_amdgcn_sched_barrier(0);
  WT0;
  __builtin_amdgcn_s_barrier();
  __builtin_amdgcn_sched_barrier(0);

#pragma unroll 1
  for (int it = 0; it < 7; ++it) {
    const int t1 = 2 * it + 1, t2 = 2 * it + 2;
    PH(0, 0, 0, 1, STAGE_A(1, t1), WT5)
    PH(0, 0, 1, 0, STAGE_B(1, t1), WTN)
    PH(0, 1, 0, 1, STN,            WTN)
    PH(0, 1, 1, 0, STN,            WTN)
    PH(1, 0, 0, 1, STAGE_A(0, t2), WT5)
    PH(1, 0, 1, 0, STAGE_B(0, t2), WTN)
    PH(1, 1, 0, 1, STN,            WTN)
    PH(1, 1, 1, 0, STN,            WTN)
  }
  // peeled last iteration (tiles 14 in buf0 already staged, 15 -> buf1)
  PH(0, 0, 0, 1, STAGE_A(1, 15), WT5)
  PH(0, 0, 1, 0, STAGE_B(1, 15), WTN)
  PH(0, 1, 0, 1, STN,            WTN)
  PH(0, 1, 1, 0, STN,            WTN)
  PH(1, 0, 0, 1, STN,            WT0)
  PH(1, 0, 1, 0, STN,            WTN)
  PH(1, 1, 0, 1, STN,            WTN)
  PH(1, 1, 1, 0, STN,            WTN)

  // ---- per-head normalization (per-element row predicate: BM=320 blocks
  //      can straddle the k/v boundary at row 12288) ----
  const int crow = (lane >> 4) * 4;
#pragma unroll
  for (int mh = 0; mh < 2; ++mh)
#pragma unroll
    for (int f = 0; f < 5; ++f) {
      const int m = mh * 5 + f;
      const int rbase = row0 + wm + mh * 80 + f * 16 + crow;
#pragma unroll
      for (int r = 0; r < 4; ++r) {
        float s = acc[m][0][r] * acc[m][0][r] + acc[m][1][r] * acc[m][1][r]
                + acc[m][2][r] * acc[m][2][r] + acc[m][3][r] * acc[m][3][r];
        s += __shfl_xor(s, 1);
        s += __shfl_xor(s, 2);
        s += __shfl_xor(s, 4);
        s += __shfl_xor(s, 8);
        if (rbase + r < RQ + RK) {
          const float inv = rsqrtf(s);
#pragma unroll
          for (int j = 0; j < 4; ++j) acc[m][j][r] *= inv;
        }
      }
    }

  // epilogue: C/D layout col=lane&15, row=(lane>>4)*4+reg
#pragma unroll
  for (int j = 0; j < 4; ++j) {
    const int col = col0 + wn + j * 16 + la15;
#pragma unroll
    for (int m = 0; m < 10; ++m) {
      const int rb = row0 + wm + (m / 5) * 80 + (m % 5) * 16 + crow;
      f16* Cp = C + (size_t)rb * DIM + col;
#pragma unroll
      for (int r = 0; r < 4; ++r) Cp[(size_t)r * DIM] = (f16)acc[m][j][r];
    }
  }
}

// ---------------------------------------------------------------------------
// MFMA fp16 GEMM (kept for the final GEMM, MT=64 path).
// ---------------------------------------------------------------------------
template <int MT, bool OUT_F16, bool NORMS, bool BIAS, bool PERB>
__global__ void __launch_bounds__(256) mfma_gemm(
    const f16* __restrict__ A, const f16* __restrict__ Bt,
    void* __restrict__ Cout, const float* __restrict__ bias) {
  constexpr int JT = (MT == 128) ? 4 : 2;
  __shared__ f16 Asl[2][MT * 32];
  __shared__ f16 Bsl[2][128 * 32];
  const int t = threadIdx.x;
  const int wid = t >> 6;
  const int lane = t & 63;
  const int row0 = blockIdx.x * MT;
  const int col0 = blockIdx.y * 128;
  const int wm = (MT == 128) ? (wid >> 1) * 64 : 0;
  const int wn = (MT == 128) ? (wid & 1) * 64 : wid * 32;

  const f16* BtB = PERB ? Bt + (size_t)(row0 >> 10) * DIM * DIM : Bt;

  const int rB = 32 * wid + (lane >> 2);
  const int qB = ((lane & 3) - ((rB >> 1) & 3)) & 3;
  const f16* gB = BtB + (size_t)(col0 + rB) * DIM + qB * 8;
  f16* lB0 = Bsl[0] + 32 * wid * 32;
  f16* lB1 = Bsl[1] + 32 * wid * 32;
  const int rA = (MT == 128 ? 32 : 16) * wid + (lane >> 2);
  const int qA = ((lane & 3) - ((rA >> 1) & 3)) & 3;
  const f16* gA = A + (size_t)(row0 + rA) * DIM + qA * 8;
  f16* lA0 = Asl[0] + (MT == 128 ? 32 : 16) * wid * 32;
  f16* lA1 = Asl[1] + (MT == 128 ? 32 : 16) * wid * 32;

  f32x4 acc[4][JT];
#pragma unroll
  for (int i = 0; i < 4; i++)
#pragma unroll
    for (int j = 0; j < JT; j++) acc[i][j] = (f32x4){0.f, 0.f, 0.f, 0.f};

  const int mrow = lane & 15;
  const int kq_p = (((lane >> 4) + ((lane >> 1) & 3)) & 3) * 8;

  for (int kt = 0; kt < DIM / 64; ++kt) {
    if (kt) __syncthreads();
    const int ko = kt * 64;
    async16(gA + ko,      lA0);
    if (MT == 128) async16(gA + ko + 16 * DIM, lA0 + 512);
    async16(gB + ko,      lB0);
    async16(gB + ko + 16 * DIM, lB0 + 512);
    async16(gA + ko + 32, lA1);
    if (MT == 128) async16(gA + ko + 32 + 16 * DIM, lA1 + 512);
    async16(gB + ko + 32, lB1);
    async16(gB + ko + 32 + 16 * DIM, lB1 + 512);
    __syncthreads();

#pragma unroll
    for (int h = 0; h < 2; ++h) {
      f16x8 af[4], bf[JT];
#pragma unroll
      for (int i = 0; i < 4; i++)
        af[i] = *(const f16x8*)(Asl[h] + (wm + i * 16 + mrow) * 32 + kq_p);
#pragma unroll
      for (int j = 0; j < JT; j++)
        bf[j] = *(const f16x8*)(Bsl[h] + (wn + j * 16 + mrow) * 32 + kq_p);
#pragma unroll
      for (int i = 0; i < 4; i++)
#pragma unroll
        for (int j = 0; j < JT; j++)
          acc[i][j] = __builtin_amdgcn_mfma_f32_16x16x32_f16(af[i], bf[j], acc[i][j], 0, 0, 0);
    }
  }

  if (NORMS && MT == 128) {
    if (row0 < RQ + RK) {
      float sums[4][4];
#pragma unroll
      for (int i = 0; i < 4; i++)
#pragma unroll
        for (int r = 0; r < 4; r++) {
          float s = 0.f;
#pragma unroll
          for (int j = 0; j < JT; j++) s += acc[i][j][r] * acc[i][j][r];
          sums[i][r] = s;
        }
#pragma unroll
      for (int off = 1; off < 16; off <<= 1)
#pragma unroll
        for (int i = 0; i < 4; i++)
#pragma unroll
          for (int r = 0; r < 4; r++)
            sums[i][r] += __shfl_xor(sums[i][r], off);
#pragma unroll
      for (int i = 0; i < 4; i++)
#pragma unroll
        for (int r = 0; r < 4; r++) {
          const float inv = rsqrtf(sums[i][r]);
#pragma unroll
          for (int j = 0; j < JT; j++) acc[i][j][r] *= inv;
        }
    }
  }

  const int ccol = lane & 15;
  const int crow = (lane >> 4) * 4;
  if (OUT_F16) {
    f16* C = (f16*)Cout;
#pragma unroll
    for (int j = 0; j < JT; j++) {
      const int col = col0 + wn + j * 16 + ccol;
#pragma unroll
      for (int i = 0; i < 4; i++) {
        f16* Cp = C + (size_t)(row0 + wm + i * 16 + crow) * DIM + col;
#pragma unroll
        for (int r = 0; r < 4; r++) Cp[(size_t)r * DIM] = (f16)acc[i][j][r];
      }
    }
  } else {
    float* C = (float*)Cout;
#pragma unroll
    for (int j = 0; j < JT; j++) {
      const int col = col0 + wn + j * 16 + ccol;
      float bv = BIAS ? bias[col] : 0.f;
#pragma unroll
      for (int i = 0; i < 4; i++) {
        float* Cp = C + (size_t)(row0 + wm + i * 16 + crow) * DIM + col;
#pragma unroll
        for (int r = 0; r < 4; r++) Cp[(size_t)r * DIM] = acc[i][j][r] + bv;
      }
    }
  }
}

// ---------------------------------------------------------------------------
// K3: per-(slice,b,h) partial S = sum over 256 m of g_k[m] outer f_v[m].
// ---------------------------------------------------------------------------
__global__ void __launch_bounds__(256) s_kernel(
    const f16* __restrict__ f, float* __restrict__ S4) {
  const int bh = blockIdx.x;
  const int b = bh >> 4, h = bh & 15;
  const int mbase = blockIdx.y * (SEQK / NSLC);
  const int t = threadIdx.x;
  __shared__ float ks[32][68];
  __shared__ float vs[32][68];
  const int lm   = t >> 3;
  const int lseg = (t & 7) * 8;
  const int d1 = (t & 15) * 4;
  const int d2 = (t >> 4) * 4;
  float acc[4][4] = {{0.f}};
  const f16* fk_base = f + ((size_t)RQ + (size_t)b * SEQK) * DIM + h * DH;
  const f16* fv_base = f + ((size_t)RQ + RK + (size_t)b * SEQK) * DIM + h * DH;

  int m = mbase + lm;
  f16x8 kv = *(const f16x8*)(fk_base + (size_t)m * DIM + lseg);
  f16x8 vv = *(const f16x8*)(fv_base + (size_t)m * DIM + lseg);

  constexpr int SUBS = SEQK / NSLC / 32;  // 8
  for (int sub = 0; sub < SUBS; ++sub) {
    __syncthreads();
#pragma unroll
    for (int e = 0; e < 8; e++) {
      ks[lm][lseg + e] = (float)kv[e];
      vs[lm][lseg + e] = (float)vv[e];
    }
    __syncthreads();
    if (sub + 1 < SUBS) {
      m = mbase + (sub + 1) * 32 + lm;
      kv = *(const f16x8*)(fk_base + (size_t)m * DIM + lseg);
      vv = *(const f16x8*)(fv_base + (size_t)m * DIM + lseg);
    }
#pragma unroll
    for (int mm = 0; mm < 32; ++mm) {
      float4 kk = *(const float4*)&ks[mm][d1];
      float4 vv2 = *(const float4*)&vs[mm][d2];
      acc[0][0] = fmaf(kk.x, vv2.x, acc[0][0]);
      acc[0][1] = fmaf(kk.x, vv2.y, acc[0][1]);
      acc[0][2] = fmaf(kk.x, vv2.z, acc[0][2]);
      acc[0][3] = fmaf(kk.x, vv2.w, acc[0][3]);
      acc[1][0] = fmaf(kk.y, vv2.x, acc[1][0]);
      acc[1][1] = fmaf(kk.y, vv2.y, acc[1][1]);
      acc[1][2] = fmaf(kk.y, vv2.z, acc[1][2]);
      acc[1][3] = fmaf(kk.y, vv2.w, acc[1][3]);
      acc[2][0] = fmaf(kk.z, vv2.x, acc[2][0]);
      acc[2][1] = fmaf(kk.z, vv2.y, acc[2][1]);
      acc[2][2] = fmaf(kk.z, vv2.z, acc[2][2]);
      acc[2][3] = fmaf(kk.z, vv2.w, acc[2][3]);
      acc[3][0] = fmaf(kk.w, vv2.x, acc[3][0]);
      acc[3][1] = fmaf(kk.w, vv2.y, acc[3][1]);
      acc[3][2] = fmaf(kk.w, vv2.z, acc[3][2]);
      acc[3][3] = fmaf(kk.w, vv2.w, acc[3][3]);
    }
  }
  float* Sp = S4 + ((size_t)blockIdx.y * BH + bh) * DH * DH;
#pragma unroll
  for (int i = 0; i < 4; i++)
#pragma unroll
    for (int j = 0; j < 4; j++)
      Sp[(d1 + i) * DH + (d2 + j)] = acc[i][j];
}

// ---------------------------------------------------------------------------
// K3b: sum the NSLC partial S slices -> Sh fp16 [bh][d1][d2] row-major.
// ---------------------------------------------------------------------------
__global__ void __launch_bounds__(256) s_reduce(
    const float* __restrict__ S4, f16* __restrict__ Sh) {
  const int bh = blockIdx.x;
  const int t = threadIdx.x;
  const size_t base = (size_t)bh * DH * DH + t * 16;
  constexpr size_t STR = (size_t)BH * DH * DH;
#pragma unroll
  for (int c = 0; c < 4; c++) {
    float4 s = {0.f, 0.f, 0.f, 0.f};
#pragma unroll
    for (int p = 0; p < NSLC; p++) {
      float4 sp = *(const float4*)(S4 + base + p * STR + 4 * c);
      s.x += sp.x; s.y += sp.y; s.z += sp.z; s.w += sp.w;
    }
    union { f16 h[4]; uint2 u; } o;
    o.h[0] = (f16)s.x; o.h[1] = (f16)s.y; o.h[2] = (f16)s.z; o.h[3] = (f16)s.w;
    *(uint2*)(Sh + base + 4 * c) = o.u;
  }
}

// ---------------------------------------------------------------------------
// K3c: Mt[b][n][64h+d1] = sum_d2 wt_out[n][64h+d2] * Sh[b,h][d1][d2]
// ---------------------------------------------------------------------------
__global__ void __launch_bounds__(256) m_build(
    const f16* __restrict__ wt_out, const f16* __restrict__ Sh,
    f16* __restrict__ Mt) {
  const int n0 = blockIdx.x * 128;
  const int bh = blockIdx.y;
  const int b = bh >> 4, h = bh & 15;
  __shared__ f16 Asl[128 * 64];
  __shared__ f16 Bsl[64 * 64];
  const int t = threadIdx.x;
  const int wid = t >> 6, lane = t & 63;

  const f16* gA = wt_out + (size_t)(n0 + 32 * wid + (lane >> 3)) * DIM
                  + 64 * h + (lane & 7) * 8;
  f16* lA = Asl + 32 * wid * 64;
  const f16* gB = Sh + (size_t)bh * DH * DH + (16 * wid + (lane >> 3)) * 64
                  + (lane & 7) * 8;
  f16* lB = Bsl + 16 * wid * 64;
#pragma unroll
  for (int o = 0; o < 4; o++) async16(gA + (size_t)(8 * o) * DIM, lA + 8 * o * 64);
  async16(gB, lB);
  async16(gB + 8 * 64, lB + 8 * 64);
  __syncthreads();

  const int wm = (wid >> 1) * 64;
  const int wn = (wid & 1) * 32;
  const int mrow = lane & 15;
  f32x4 acc[4][2];
#pragma unroll
  for (int i = 0; i < 4; i++)
#pragma unroll
    for (int j = 0; j < 2; j++) acc[i][j] = (f32x4){0.f, 0.f, 0.f, 0.f};

#pragma unroll
  for (int kh = 0; kh < 2; kh++) {
    const int kq = kh * 32 + (lane >> 4) * 8;
    f16x8 af[4], bf[2];
#pragma unroll
    for (int i = 0; i < 4; i++)
      af[i] = *(const f16x8*)(Asl + (wm + i * 16 + mrow) * 64 + kq);
#pragma unroll
    for (int j = 0; j < 2; j++)
      bf[j] = *(const f16x8*)(Bsl + (wn + j * 16 + mrow) * 64 + kq);
#pragma unroll
    for (int i = 0; i < 4; i++)
#pragma unroll
      for (int j = 0; j < 2; j++)
        acc[i][j] = __builtin_amdgcn_mfma_f32_16x16x32_f16(af[i], bf[j], acc[i][j], 0, 0, 0);
  }

  const int ccol = lane & 15;
  const int crow = (lane >> 4) * 4;
  f16* Mb = Mt + (size_t)b * DIM * DIM;
#pragma unroll
  for (int j = 0; j < 2; j++) {
    const int col = 64 * h + wn + j * 16 + ccol;
#pragma unroll
    for (int i = 0; i < 4; i++) {
      f16* Mp = Mb + (size_t)(n0 + wm + i * 16 + crow) * DIM + col;
#pragma unroll
      for (int r = 0; r < 4; r++) Mp[(size_t)r * DIM] = (f16)acc[i][j][r];
    }
  }
}

// ---------------------------------------------------------------------------
extern "C" void kernel_launch(void* const* d_in, const int* in_sizes, int n_in,
                              void* d_out, int out_size, void* d_ws, size_t ws_size,
                              hipStream_t stream) {
  const float* q     = (const float*)d_in[0];
  const float* k     = (const float*)d_in[1];
  const float* v     = (const float*)d_in[2];
  const float* gamma = (const float*)d_in[3];
  const float* beta  = (const float*)d_in[4];
  const float* W_in  = (const float*)d_in[5];
  const float* W_out = (const float*)d_in[6];
  const float* b_out = (const float*)d_in[7];
  float* out = (float*)d_out;

  // workspace layout
  char* w = (char*)d_ws;
  f16*   f      = (f16*)w;                                     // 40 MB
  f16*   a_h    = f + (size_t)RTOT * DIM;                      // 40 MB
  f16*   wt_in  = a_h + (size_t)RTOT * DIM;                    // 2 MB
  f16*   wt_out = wt_in + (size_t)DIM * DIM;                   // 2 MB
  f16*   Mt     = wt_out + (size_t)DIM * DIM;                  // 8 MB
  f16*   Sh     = Mt + (size_t)BATCH * DIM * DIM;              // 512 KB
  float* S4     = (float*)(Sh + (size_t)BH * DH * DH);         // 8 MB

  ln_to_f16<<<RTOT / 4, 256, 0, stream>>>(q, k, v, gamma, beta, a_h);
  transpose_f16<<<dim3(DIM / 32, DIM / 32, 2), 256, 0, stream>>>(
      W_in, W_out, wt_in, wt_out);

  // f = LN(t) @ W_in for all rows; q/k rows pre-normalized per head
  proj_gemm<<<dim3(256), 512, 0, stream>>>(a_h, wt_in, f);

  s_kernel<<<dim3(BH, NSLC), 256, 0, stream>>>(f, S4);

  s_reduce<<<BH, 256, 0, stream>>>(S4, Sh);

  m_build<<<dim3(DIM / 128, BH), 256, 0, stream>>>(wt_out, Sh, Mt);

  // out = g_q @ Mt[b]^T + b_out (per-batch weights)
  mfma_gemm<64, false, false, true, true>
      <<<dim3(RQ / 64, DIM / 128), 256, 0, stream>>>(f, Mt, out, b_out);
}

// Round 3
// 232.930 us; speedup vs baseline: 1.0722x; 1.0257x over previous
//
#include <hip/hip_runtime.h>

// Problem constants
constexpr int BATCH = 4;
constexpr int SEQQ  = 1024;
constexpr int SEQK  = 2048;
constexpr int DIM   = 1024;
constexpr int NH    = 16;
constexpr int DH    = 64;
constexpr int RQ    = BATCH * SEQQ;          // 4096 q rows
constexpr int RK    = BATCH * SEQK;          // 8192 k rows (== v rows)
constexpr int RTOT  = RQ + 2 * RK;           // 20480
constexpr int BH    = BATCH * NH;            // 64
constexpr int NSLC  = 8;                     // s_kernel K-slices
constexpr float LN_EPS = 1e-5f;

typedef _Float16 f16;
typedef __attribute__((ext_vector_type(8))) _Float16 f16x8;
typedef __attribute__((ext_vector_type(4))) float f32x4;

__device__ __forceinline__ void async16(const void* g, void* l) {
  __builtin_amdgcn_global_load_lds(
      (const __attribute__((address_space(1))) void*)g,
      (__attribute__((address_space(3))) void*)l, 16, 0, 0);
}

// ---------------------------------------------------------------------------
// K0: fused LayerNorm -> fp16. One wave per row (no LDS, no barriers).
// ---------------------------------------------------------------------------
__global__ void __launch_bounds__(256) ln_to_f16(
    const float* __restrict__ q, const float* __restrict__ k,
    const float* __restrict__ v, const float* __restrict__ gamma,
    const float* __restrict__ beta, f16* __restrict__ a_h) {
  const int row = blockIdx.x * 4 + (threadIdx.x >> 6);
  const int lane = threadIdx.x & 63;
  const float* src;
  if (row < RQ)            src = q + (size_t)row * DIM;
  else if (row < RQ + RK)  src = k + (size_t)(row - RQ) * DIM;
  else                     src = v + (size_t)(row - RQ - RK) * DIM;
  float4 x[4];
  float s = 0.f, s2 = 0.f;
#pragma unroll
  for (int c = 0; c < 4; c++) {
    x[c] = ((const float4*)src)[c * 64 + lane];
    s  += x[c].x + x[c].y + x[c].z + x[c].w;
    s2 += x[c].x * x[c].x + x[c].y * x[c].y + x[c].z * x[c].z + x[c].w * x[c].w;
  }
#pragma unroll
  for (int off = 1; off < 64; off <<= 1) {
    s  += __shfl_xor(s, off);
    s2 += __shfl_xor(s2, off);
  }
  const float mu = s / DIM;
  const float rs = rsqrtf(s2 / DIM - mu * mu + LN_EPS);
#pragma unroll
  for (int c = 0; c < 4; c++) {
    float4 g = ((const float4*)gamma)[c * 64 + lane];
    float4 b = ((const float4*)beta)[c * 64 + lane];
    union { f16 h[4]; uint2 u; } o;
    o.h[0] = (f16)((x[c].x - mu) * rs * g.x + b.x);
    o.h[1] = (f16)((x[c].y - mu) * rs * g.y + b.y);
    o.h[2] = (f16)((x[c].z - mu) * rs * g.z + b.z);
    o.h[3] = (f16)((x[c].w - mu) * rs * g.w + b.w);
    ((uint2*)(a_h + (size_t)row * DIM))[c * 64 + lane] = o.u;
  }
}

// ---------------------------------------------------------------------------
// K0b: transpose + fp16 convert of W_in and W_out (1024x1024 each).
// ---------------------------------------------------------------------------
__global__ void __launch_bounds__(256) transpose_f16(
    const float* __restrict__ W0, const float* __restrict__ W1,
    f16* __restrict__ T0, f16* __restrict__ T1) {
  const float* W = blockIdx.z ? W1 : W0;
  f16* T = blockIdx.z ? T1 : T0;
  __shared__ float tile[32][33];
  int tx = threadIdx.x & 31, ty = threadIdx.x >> 5;
  int k0 = blockIdx.x * 32, n0 = blockIdx.y * 32;
#pragma unroll
  for (int i = 0; i < 4; i++)
    tile[ty + 8 * i][tx] = W[(size_t)(k0 + ty + 8 * i) * DIM + n0 + tx];
  __syncthreads();
#pragma unroll
  for (int i = 0; i < 4; i++)
    T[(size_t)(n0 + ty + 8 * i) * DIM + k0 + tx] = (f16)tile[tx][ty + 8 * i];
}

// ---------------------------------------------------------------------------
// K1: projection GEMM, 320x256 tile -> grid 256 blocks = 1 per CU.
//     4 merged phases per 2-K-tile iteration (was 8), 2 barriers per phase.
//
//   f[RTOT x 1024] = a_h[RTOT x 1024] @ wt_in^T; q/k rows pre-normalized
//   per head (wave's 64-col span = one head).
//
// Geometry: 8 waves (2M x 4N); per-wave 160x64 out, acc[10][4] f32x4.
// LDS 144 KiB: A 2 tile-bufs x [320][64], B 2 x [256][64], f16.
// Chunk swizzle: 16B chunk c' = (half*4+slot) ^ (row&7) applied to BOTH
// the staging source address and the ds_read address (2 lanes/bank, free).
//
// Phases Q1..Q4 = (buf, K-half), both mh halves computed per phase
// (40 MFMA, 14 ds_read_b128; compiler's counted lgkmcnt overlaps the
// af1 reads with the mh0 MFMA block). Stage/wait schedule per iter:
//   Q1 (buf0,K0): stage A(2it+1)->buf1; vmcnt(5)  [drains A,B of tile 2it]
//   Q2 (buf0,K1): stage B(2it+1)->buf1
//   Q3 (buf1,K0): stage A(2it+2)->buf0; vmcnt(5)  [drains A,B of 2it+1]
//   Q4 (buf1,K1): stage B(2it+2)->buf0
// Stage->consume distance = 2 phases (~3000cy >> HBM 900cy). Overwrite
// safety: each stage targets the buffer whose last read ended >=1
// barrier earlier. Last iteration peeled (Q3 waits vmcnt(0)).
//
// Epilogue: per m-group (10 of 16 rows x 256 cols), acc -> LDS scratch
// (reuses As, stride 264 to spread banks) -> 16B-contiguous global
// stores so every 64B line is produced whole (fixes the 2.3x HBM write
// amplification seen at 32 blocks/XCD where dirty C overflows L2).
// ---------------------------------------------------------------------------
constexpr int PT_A = 320 * 64;   // f16 per A tile buffer (20480)
constexpr int PT_B = 256 * 64;   // f16 per B tile buffer (16384)

#define STAGE_A(buf, kt) do {                                        \
    const f16* s_ = gA + (size_t)(kt) * 64;                          \
    f16* d_ = AsW + (buf) * PT_A;                                    \
    async16(s_,          d_);                                        \
    async16(s_ +  65536, d_ + 4096);                                 \
    async16(s_ + 131072, d_ + 8192);                                 \
    async16(s_ + 196608, d_ + 12288);                                \
    async16(s_ + 262144, d_ + 16384);                                \
  } while (0)

#define STAGE_B(buf, kt) do {                                        \
    const f16* s_ = gB + (size_t)(kt) * 64;                          \
    f16* d_ = BsW + (buf) * PT_B;                                    \
    async16(s_,          d_);                                        \
    async16(s_ +  65536, d_ + 4096);                                 \
    async16(s_ + 131072, d_ + 8192);                                 \
    async16(s_ + 196608, d_ + 12288);                                \
  } while (0)

#define WT5 asm volatile("s_waitcnt vmcnt(5)" ::: "memory")
#define WT0 asm volatile("s_waitcnt vmcnt(0)" ::: "memory")
#define WTN ((void)0)
#define STN ((void)0)

#define PH2(BUF, H, STG, WT) {                                       \
    STG;                                                             \
    __builtin_amdgcn_sched_barrier(0);                               \
    WT;                                                              \
    __builtin_amdgcn_s_barrier();                                    \
    __builtin_amdgcn_sched_barrier(0);                               \
    _Pragma("unroll") for (int j_ = 0; j_ < 4; ++j_)                 \
      bf[j_] = *(const f16x8*)(bB##H + (BUF) * PT_B + j_ * 1024);    \
    _Pragma("unroll") for (int f_ = 0; f_ < 5; ++f_)                 \
      af0[f_] = *(const f16x8*)(aB##H + (BUF) * PT_A + f_ * 1024);   \
    _Pragma("unroll") for (int f_ = 0; f_ < 5; ++f_)                 \
      af1[f_] = *(const f16x8*)(aB##H + (BUF) * PT_A + 5120 +        \
                                f_ * 1024);                          \
    __builtin_amdgcn_s_setprio(1);                                   \
    _Pragma("unroll") for (int f_ = 0; f_ < 5; ++f_)                 \
      _Pragma("unroll") for (int j_ = 0; j_ < 4; ++j_)               \
        acc[f_][j_] = __builtin_amdgcn_mfma_f32_16x16x32_f16(        \
            af0[f_], bf[j_], acc[f_][j_], 0, 0, 0);                  \
    _Pragma("unroll") for (int f_ = 0; f_ < 5; ++f_)                 \
      _Pragma("unroll") for (int j_ = 0; j_ < 4; ++j_)               \
        acc[5 + f_][j_] = __builtin_amdgcn_mfma_f32_16x16x32_f16(    \
            af1[f_], bf[j_], acc[5 + f_][j_], 0, 0, 0);              \
    __builtin_amdgcn_s_setprio(0);                                   \
    __builtin_amdgcn_sched_barrier(0);                               \
    __builtin_amdgcn_s_barrier();                                    \
  }

__global__ void __launch_bounds__(512, 2) proj_gemm(
    const f16* __restrict__ A, const f16* __restrict__ Bt,
    f16* __restrict__ C) {
  __shared__ __align__(16) f16 As[2 * PT_A];   // 80 KB
  __shared__ __align__(16) f16 Bs[2 * PT_B];   // 64 KB

  const int tid = threadIdx.x;
  const int wid = tid >> 6;
  const int lane = tid & 63;
  const int la15 = lane & 15;

  // bijective XCD swizzle (256 % 8 == 0); col-tile fastest within an XCD
  // chunk so a row-panel's 4 column tiles share one XCD's L2.
  const int bid = blockIdx.x;
  const int swz = (bid & 7) * 32 + (bid >> 3);
  const int row0 = (swz >> 2) * 320;
  const int col0 = (swz & 3) * 256;

  const int wm = (wid >> 2) * 160;      // warp_m in {0,1}
  const int wn = (wid & 3) * 64;        // warp_n in {0..3}

  // ---- staging source (per-thread), chunk-XOR pre-applied to source ----
  const int hs = (tid & 7) ^ ((tid >> 3) & 7);
  const f16* gA = A + (size_t)(row0 + (tid >> 3)) * DIM + (hs >> 2) * 32 +
                  (hs & 3) * 8;
  const f16* gB = Bt + (size_t)(col0 + (tid >> 3)) * DIM + (hs >> 2) * 32 +
                  (hs & 3) * 8;
  f16* AsW = As + wid * 512;            // wave-uniform LDS dest bases
  f16* BsW = Bs + wid * 512;

  // ---- fragment read bases (per half), XOR folded per-thread ----
  const int g = lane >> 4;
  const int r7 = la15 & 7;
  const int cs0 = (g ^ r7) * 8;             // half 0 chunk
  const int cs1 = ((4 + g) ^ r7) * 8;       // half 1 chunk
  const f16* aB0 = As + (wm + la15) * 64 + cs0;
  const f16* aB1 = As + (wm + la15) * 64 + cs1;
  const f16* bB0 = Bs + (wn + la15) * 64 + cs0;
  const f16* bB1 = Bs + (wn + la15) * 64 + cs1;

  f32x4 acc[10][4];
#pragma unroll
  for (int i = 0; i < 10; i++)
#pragma unroll
    for (int j = 0; j < 4; j++) acc[i][j] = (f32x4){0.f, 0.f, 0.f, 0.f};
  f16x8 af0[5], af1[5], bf[4];

  // prologue: tile 0 into buf0, drain fully
  STAGE_A(0, 0);
  STAGE_B(0, 0);
  __builtin_amdgcn_sched_barrier(0);
  WT0;
  __builtin_amdgcn_s_barrier();
  __builtin_amdgcn_sched_barrier(0);

#pragma unroll 1
  for (int it = 0; it < 7; ++it) {
    const int t1 = 2 * it + 1, t2 = 2 * it + 2;
    PH2(0, 0, STAGE_A(1, t1), WT5)
    PH2(0, 1, STAGE_B(1, t1), WTN)
    PH2(1, 0, STAGE_A(0, t2), WT5)
    PH2(1, 1, STAGE_B(0, t2), WTN)
  }
  // peeled last iteration (tile 14 in buf0, tile 15 -> buf1)
  PH2(0, 0, STAGE_A(1, 15), WT5)
  PH2(0, 1, STAGE_B(1, 15), WTN)
  PH2(1, 0, STN,            WT0)
  PH2(1, 1, STN,            WTN)

  // ---- per-head normalization (per-element row predicate: BM=320 blocks
  //      can straddle the k/v boundary at row 12288) ----
  const int crow = (lane >> 4) * 4;
#pragma unroll
  for (int mh = 0; mh < 2; ++mh)
#pragma unroll
    for (int f = 0; f < 5; ++f) {
      const int m = mh * 5 + f;
      const int rbase = row0 + wm + mh * 80 + f * 16 + crow;
#pragma unroll
      for (int r = 0; r < 4; ++r) {
        float s = acc[m][0][r] * acc[m][0][r] + acc[m][1][r] * acc[m][1][r]
                + acc[m][2][r] * acc[m][2][r] + acc[m][3][r] * acc[m][3][r];
        s += __shfl_xor(s, 1);
        s += __shfl_xor(s, 2);
        s += __shfl_xor(s, 4);
        s += __shfl_xor(s, 8);
        if (rbase + r < RQ + RK) {
          const float inv = rsqrtf(s);
#pragma unroll
          for (int j = 0; j < 4; ++j) acc[m][j][r] *= inv;
        }
      }
    }

  // ---- epilogue: LDS-transpose to full-line 16B-contiguous stores ----
  // scratch overlays As: [2 halves][16 rows][264 cols] f16 (16.9 KB)
  f16* sc = As;
  const int wmi = wid >> 2;
  const int ehalf = tid >> 8;
  const int err = (tid >> 4) & 15;
  const int ecc = tid & 15;
  const f16* rb_l = sc + ehalf * (16 * 264) + err * 264 + ecc * 16;
#pragma unroll
  for (int mh = 0; mh < 2; ++mh)
#pragma unroll
    for (int f = 0; f < 5; ++f) {
      const int m = mh * 5 + f;
#pragma unroll
      for (int j = 0; j < 4; ++j)
#pragma unroll
        for (int r = 0; r < 4; ++r)
          sc[wmi * (16 * 264) + (crow + r) * 264 + wn + j * 16 + la15] =
              (f16)acc[m][j][r];
      __syncthreads();
      f16x8 v0 = *(const f16x8*)(rb_l);
      f16x8 v1 = *(const f16x8*)(rb_l + 8);
      const int grow = row0 + ehalf * 160 + mh * 80 + f * 16 + err;
      f16* Cp = C + (size_t)grow * DIM + col0 + ecc * 16;
      *(f16x8*)(Cp) = v0;
      *(f16x8*)(Cp + 8) = v1;
      if (!(mh == 1 && f == 4)) __syncthreads();
    }
}

// ---------------------------------------------------------------------------
// MFMA fp16 GEMM (kept for the final GEMM, MT=64 path).
// ---------------------------------------------------------------------------
template <int MT, bool OUT_F16, bool NORMS, bool BIAS, bool PERB>
__global__ void __launch_bounds__(256) mfma_gemm(
    const f16* __restrict__ A, const f16* __restrict__ Bt,
    void* __restrict__ Cout, const float* __restrict__ bias) {
  constexpr int JT = (MT == 128) ? 4 : 2;
  __shared__ f16 Asl[2][MT * 32];
  __shared__ f16 Bsl[2][128 * 32];
  const int t = threadIdx.x;
  const int wid = t >> 6;
  const int lane = t & 63;
  const int row0 = blockIdx.x * MT;
  const int col0 = blockIdx.y * 128;
  const int wm = (MT == 128) ? (wid >> 1) * 64 : 0;
  const int wn = (MT == 128) ? (wid & 1) * 64 : wid * 32;

  const f16* BtB = PERB ? Bt + (size_t)(row0 >> 10) * DIM * DIM : Bt;

  const int rB = 32 * wid + (lane >> 2);
  const int qB = ((lane & 3) - ((rB >> 1) & 3)) & 3;
  const f16* gB = BtB + (size_t)(col0 + rB) * DIM + qB * 8;
  f16* lB0 = Bsl[0] + 32 * wid * 32;
  f16* lB1 = Bsl[1] + 32 * wid * 32;
  const int rA = (MT == 128 ? 32 : 16) * wid + (lane >> 2);
  const int qA = ((lane & 3) - ((rA >> 1) & 3)) & 3;
  const f16* gA = A + (size_t)(row0 + rA) * DIM + qA * 8;
  f16* lA0 = Asl[0] + (MT == 128 ? 32 : 16) * wid * 32;
  f16* lA1 = Asl[1] + (MT == 128 ? 32 : 16) * wid * 32;

  f32x4 acc[4][JT];
#pragma unroll
  for (int i = 0; i < 4; i++)
#pragma unroll
    for (int j = 0; j < JT; j++) acc[i][j] = (f32x4){0.f, 0.f, 0.f, 0.f};

  const int mrow = lane & 15;
  const int kq_p = (((lane >> 4) + ((lane >> 1) & 3)) & 3) * 8;

  for (int kt = 0; kt < DIM / 64; ++kt) {
    if (kt) __syncthreads();
    const int ko = kt * 64;
    async16(gA + ko,      lA0);
    if (MT == 128) async16(gA + ko + 16 * DIM, lA0 + 512);
    async16(gB + ko,      lB0);
    async16(gB + ko + 16 * DIM, lB0 + 512);
    async16(gA + ko + 32, lA1);
    if (MT == 128) async16(gA + ko + 32 + 16 * DIM, lA1 + 512);
    async16(gB + ko + 32, lB1);
    async16(gB + ko + 32 + 16 * DIM, lB1 + 512);
    __syncthreads();

#pragma unroll
    for (int h = 0; h < 2; ++h) {
      f16x8 af[4], bf[JT];
#pragma unroll
      for (int i = 0; i < 4; i++)
        af[i] = *(const f16x8*)(Asl[h] + (wm + i * 16 + mrow) * 32 + kq_p);
#pragma unroll
      for (int j = 0; j < JT; j++)
        bf[j] = *(const f16x8*)(Bsl[h] + (wn + j * 16 + mrow) * 32 + kq_p);
#pragma unroll
      for (int i = 0; i < 4; i++)
#pragma unroll
        for (int j = 0; j < JT; j++)
          acc[i][j] = __builtin_amdgcn_mfma_f32_16x16x32_f16(af[i], bf[j], acc[i][j], 0, 0, 0);
    }
  }

  if (NORMS && MT == 128) {
    if (row0 < RQ + RK) {
      float sums[4][4];
#pragma unroll
      for (int i = 0; i < 4; i++)
#pragma unroll
        for (int r = 0; r < 4; r++) {
          float s = 0.f;
#pragma unroll
          for (int j = 0; j < JT; j++) s += acc[i][j][r] * acc[i][j][r];
          sums[i][r] = s;
        }
#pragma unroll
      for (int off = 1; off < 16; off <<= 1)
#pragma unroll
        for (int i = 0; i < 4; i++)
#pragma unroll
          for (int r = 0; r < 4; r++)
            sums[i][r] += __shfl_xor(sums[i][r], off);
#pragma unroll
      for (int i = 0; i < 4; i++)
#pragma unroll
        for (int r = 0; r < 4; r++) {
          const float inv = rsqrtf(sums[i][r]);
#pragma unroll
          for (int j = 0; j < JT; j++) acc[i][j][r] *= inv;
        }
    }
  }

  const int ccol = lane & 15;
  const int crow = (lane >> 4) * 4;
  if (OUT_F16) {
    f16* C = (f16*)Cout;
#pragma unroll
    for (int j = 0; j < JT; j++) {
      const int col = col0 + wn + j * 16 + ccol;
#pragma unroll
      for (int i = 0; i < 4; i++) {
        f16* Cp = C + (size_t)(row0 + wm + i * 16 + crow) * DIM + col;
#pragma unroll
        for (int r = 0; r < 4; r++) Cp[(size_t)r * DIM] = (f16)acc[i][j][r];
      }
    }
  } else {
    float* C = (float*)Cout;
#pragma unroll
    for (int j = 0; j < JT; j++) {
      const int col = col0 + wn + j * 16 + ccol;
      float bv = BIAS ? bias[col] : 0.f;
#pragma unroll
      for (int i = 0; i < 4; i++) {
        float* Cp = C + (size_t)(row0 + wm + i * 16 + crow) * DIM + col;
#pragma unroll
        for (int r = 0; r < 4; r++) Cp[(size_t)r * DIM] = acc[i][j][r] + bv;
      }
    }
  }
}

// ---------------------------------------------------------------------------
// K3: per-(slice,b,h) partial S = sum over 256 m of g_k[m] outer f_v[m].
// ---------------------------------------------------------------------------
__global__ void __launch_bounds__(256) s_kernel(
    const f16* __restrict__ f, float* __restrict__ S4) {
  const int bh = blockIdx.x;
  const int b = bh >> 4, h = bh & 15;
  const int mbase = blockIdx.y * (SEQK / NSLC);
  const int t = threadIdx.x;
  __shared__ float ks[32][68];
  __shared__ float vs[32][68];
  const int lm   = t >> 3;
  const int lseg = (t & 7) * 8;
  const int d1 = (t & 15) * 4;
  const int d2 = (t >> 4) * 4;
  float acc[4][4] = {{0.f}};
  const f16* fk_base = f + ((size_t)RQ + (size_t)b * SEQK) * DIM + h * DH;
  const f16* fv_base = f + ((size_t)RQ + RK + (size_t)b * SEQK) * DIM + h * DH;

  int m = mbase + lm;
  f16x8 kv = *(const f16x8*)(fk_base + (size_t)m * DIM + lseg);
  f16x8 vv = *(const f16x8*)(fv_base + (size_t)m * DIM + lseg);

  constexpr int SUBS = SEQK / NSLC / 32;  // 8
  for (int sub = 0; sub < SUBS; ++sub) {
    __syncthreads();
#pragma unroll
    for (int e = 0; e < 8; e++) {
      ks[lm][lseg + e] = (float)kv[e];
      vs[lm][lseg + e] = (float)vv[e];
    }
    __syncthreads();
    if (sub + 1 < SUBS) {
      m = mbase + (sub + 1) * 32 + lm;
      kv = *(const f16x8*)(fk_base + (size_t)m * DIM + lseg);
      vv = *(const f16x8*)(fv_base + (size_t)m * DIM + lseg);
    }
#pragma unroll
    for (int mm = 0; mm < 32; ++mm) {
      float4 kk = *(const float4*)&ks[mm][d1];
      float4 vv2 = *(const float4*)&vs[mm][d2];
      acc[0][0] = fmaf(kk.x, vv2.x, acc[0][0]);
      acc[0][1] = fmaf(kk.x, vv2.y, acc[0][1]);
      acc[0][2] = fmaf(kk.x, vv2.z, acc[0][2]);
      acc[0][3] = fmaf(kk.x, vv2.w, acc[0][3]);
      acc[1][0] = fmaf(kk.y, vv2.x, acc[1][0]);
      acc[1][1] = fmaf(kk.y, vv2.y, acc[1][1]);
      acc[1][2] = fmaf(kk.y, vv2.z, acc[1][2]);
      acc[1][3] = fmaf(kk.y, vv2.w, acc[1][3]);
      acc[2][0] = fmaf(kk.z, vv2.x, acc[2][0]);
      acc[2][1] = fmaf(kk.z, vv2.y, acc[2][1]);
      acc[2][2] = fmaf(kk.z, vv2.z, acc[2][2]);
      acc[2][3] = fmaf(kk.z, vv2.w, acc[2][3]);
      acc[3][0] = fmaf(kk.w, vv2.x, acc[3][0]);
      acc[3][1] = fmaf(kk.w, vv2.y, acc[3][1]);
      acc[3][2] = fmaf(kk.w, vv2.z, acc[3][2]);
      acc[3][3] = fmaf(kk.w, vv2.w, acc[3][3]);
    }
  }
  float* Sp = S4 + ((size_t)blockIdx.y * BH + bh) * DH * DH;
#pragma unroll
  for (int i = 0; i < 4; i++)
#pragma unroll
    for (int j = 0; j < 4; j++)
      Sp[(d1 + i) * DH + (d2 + j)] = acc[i][j];
}

// ---------------------------------------------------------------------------
// K3b: sum the NSLC partial S slices -> Sh fp16 [bh][d1][d2] row-major.
// ---------------------------------------------------------------------------
__global__ void __launch_bounds__(256) s_reduce(
    const float* __restrict__ S4, f16* __restrict__ Sh) {
  const int bh = blockIdx.x;
  const int t = threadIdx.x;
  const size_t base = (size_t)bh * DH * DH + t * 16;
  constexpr size_t STR = (size_t)BH * DH * DH;
#pragma unroll
  for (int c = 0; c < 4; c++) {
    float4 s = {0.f, 0.f, 0.f, 0.f};
#pragma unroll
    for (int p = 0; p < NSLC; p++) {
      float4 sp = *(const float4*)(S4 + base + p * STR + 4 * c);
      s.x += sp.x; s.y += sp.y; s.z += sp.z; s.w += sp.w;
    }
    union { f16 h[4]; uint2 u; } o;
    o.h[0] = (f16)s.x; o.h[1] = (f16)s.y; o.h[2] = (f16)s.z; o.h[3] = (f16)s.w;
    *(uint2*)(Sh + base + 4 * c) = o.u;
  }
}

// ---------------------------------------------------------------------------
// K3c: Mt[b][n][64h+d1] = sum_d2 wt_out[n][64h+d2] * Sh[b,h][d1][d2]
// ---------------------------------------------------------------------------
__global__ void __launch_bounds__(256) m_build(
    const f16* __restrict__ wt_out, const f16* __restrict__ Sh,
    f16* __restrict__ Mt) {
  const int n0 = blockIdx.x * 128;
  const int bh = blockIdx.y;
  const int b = bh >> 4, h = bh & 15;
  __shared__ f16 Asl[128 * 64];
  __shared__ f16 Bsl[64 * 64];
  const int t = threadIdx.x;
  const int wid = t >> 6, lane = t & 63;

  const f16* gA = wt_out + (size_t)(n0 + 32 * wid + (lane >> 3)) * DIM
                  + 64 * h + (lane & 7) * 8;
  f16* lA = Asl + 32 * wid * 64;
  const f16* gB = Sh + (size_t)bh * DH * DH + (16 * wid + (lane >> 3)) * 64
                  + (lane & 7) * 8;
  f16* lB = Bsl + 16 * wid * 64;
#pragma unroll
  for (int o = 0; o < 4; o++) async16(gA + (size_t)(8 * o) * DIM, lA + 8 * o * 64);
  async16(gB, lB);
  async16(gB + 8 * 64, lB + 8 * 64);
  __syncthreads();

  const int wm = (wid >> 1) * 64;
  const int wn = (wid & 1) * 32;
  const int mrow = lane & 15;
  f32x4 acc[4][2];
#pragma unroll
  for (int i = 0; i < 4; i++)
#pragma unroll
    for (int j = 0; j < 2; j++) acc[i][j] = (f32x4){0.f, 0.f, 0.f, 0.f};

#pragma unroll
  for (int kh = 0; kh < 2; kh++) {
    const int kq = kh * 32 + (lane >> 4) * 8;
    f16x8 af[4], bf[2];
#pragma unroll
    for (int i = 0; i < 4; i++)
      af[i] = *(const f16x8*)(Asl + (wm + i * 16 + mrow) * 64 + kq);
#pragma unroll
    for (int j = 0; j < 2; j++)
      bf[j] = *(const f16x8*)(Bsl + (wn + j * 16 + mrow) * 64 + kq);
#pragma unroll
    for (int i = 0; i < 4; i++)
#pragma unroll
      for (int j = 0; j < 2; j++)
        acc[i][j] = __builtin_amdgcn_mfma_f32_16x16x32_f16(af[i], bf[j], acc[i][j], 0, 0, 0);
  }

  const int ccol = lane & 15;
  const int crow = (lane >> 4) * 4;
  f16* Mb = Mt + (size_t)b * DIM * DIM;
#pragma unroll
  for (int j = 0; j < 2; j++) {
    const int col = 64 * h + wn + j * 16 + ccol;
#pragma unroll
    for (int i = 0; i < 4; i++) {
      f16* Mp = Mb + (size_t)(n0 + wm + i * 16 + crow) * DIM + col;
#pragma unroll
      for (int r = 0; r < 4; r++) Mp[(size_t)r * DIM] = (f16)acc[i][j][r];
    }
  }
}

// ---------------------------------------------------------------------------
extern "C" void kernel_launch(void* const* d_in, const int* in_sizes, int n_in,
                              void* d_out, int out_size, void* d_ws, size_t ws_size,
                              hipStream_t stream) {
  const float* q     = (const float*)d_in[0];
  const float* k     = (const float*)d_in[1];
  const float* v     = (const float*)d_in[2];
  const float* gamma = (const float*)d_in[3];
  const float* beta  = (const float*)d_in[4];
  const float* W_in  = (const float*)d_in[5];
  const float* W_out = (const float*)d_in[6];
  const float* b_out = (const float*)d_in[7];
  float* out = (float*)d_out;

  // workspace layout
  char* w = (char*)d_ws;
  f16*   f      = (f16*)w;                                     // 40 MB
  f16*   a_h    = f + (size_t)RTOT * DIM;                      // 40 MB
  f16*   wt_in  = a_h + (size_t)RTOT * DIM;                    // 2 MB
  f16*   wt_out = wt_in + (size_t)DIM * DIM;                   // 2 MB
  f16*   Mt     = wt_out + (size_t)DIM * DIM;                  // 8 MB
  f16*   Sh     = Mt + (size_t)BATCH * DIM * DIM;              // 512 KB
  float* S4     = (float*)(Sh + (size_t)BH * DH * DH);         // 8 MB

  ln_to_f16<<<RTOT / 4, 256, 0, stream>>>(q, k, v, gamma, beta, a_h);
  transpose_f16<<<dim3(DIM / 32, DIM / 32, 2), 256, 0, stream>>>(
      W_in, W_out, wt_in, wt_out);

  // f = LN(t) @ W_in for all rows; q/k rows pre-normalized per head
  proj_gemm<<<dim3(256), 512, 0, stream>>>(a_h, wt_in, f);

  s_kernel<<<dim3(BH, NSLC), 256, 0, stream>>>(f, S4);

  s_reduce<<<BH, 256, 0, stream>>>(S4, Sh);

  m_build<<<dim3(DIM / 128, BH), 256, 0, stream>>>(wt_out, Sh, Mt);

  // out = g_q @ Mt[b]^T + b_out (per-batch weights)
  mfma_gemm<64, false, false, true, true>
      <<<dim3(RQ / 64, DIM / 128), 256, 0, stream>>>(f, Mt, out, b_out);
}

// Round 4
// 231.661 us; speedup vs baseline: 1.0781x; 1.0055x over previous
//
#include <hip/hip_runtime.h>

// Problem constants
constexpr int BATCH = 4;
constexpr int SEQQ  = 1024;
constexpr int SEQK  = 2048;
constexpr int DIM   = 1024;
constexpr int NH    = 16;
constexpr int DH    = 64;
constexpr int RQ    = BATCH * SEQQ;          // 4096 q rows
constexpr int RK    = BATCH * SEQK;          // 8192 k rows (== v rows)
constexpr int RTOT  = RQ + 2 * RK;           // 20480
constexpr int BH    = BATCH * NH;            // 64
constexpr int NSLC  = 8;                     // s_kernel K-slices
constexpr float LN_EPS = 1e-5f;

typedef _Float16 f16;
typedef __attribute__((ext_vector_type(8))) _Float16 f16x8;
typedef __attribute__((ext_vector_type(4))) float f32x4;

__device__ __forceinline__ void async16(const void* g, void* l) {
  __builtin_amdgcn_global_load_lds(
      (const __attribute__((address_space(1))) void*)g,
      (__attribute__((address_space(3))) void*)l, 16, 0, 0);
}

// ---------------------------------------------------------------------------
// K0: fused LayerNorm -> fp16. One wave per row (no LDS, no barriers).
// ---------------------------------------------------------------------------
__global__ void __launch_bounds__(256) ln_to_f16(
    const float* __restrict__ q, const float* __restrict__ k,
    const float* __restrict__ v, const float* __restrict__ gamma,
    const float* __restrict__ beta, f16* __restrict__ a_h) {
  const int row = blockIdx.x * 4 + (threadIdx.x >> 6);
  const int lane = threadIdx.x & 63;
  const float* src;
  if (row < RQ)            src = q + (size_t)row * DIM;
  else if (row < RQ + RK)  src = k + (size_t)(row - RQ) * DIM;
  else                     src = v + (size_t)(row - RQ - RK) * DIM;
  float4 x[4];
  float s = 0.f, s2 = 0.f;
#pragma unroll
  for (int c = 0; c < 4; c++) {
    x[c] = ((const float4*)src)[c * 64 + lane];
    s  += x[c].x + x[c].y + x[c].z + x[c].w;
    s2 += x[c].x * x[c].x + x[c].y * x[c].y + x[c].z * x[c].z + x[c].w * x[c].w;
  }
#pragma unroll
  for (int off = 1; off < 64; off <<= 1) {
    s  += __shfl_xor(s, off);
    s2 += __shfl_xor(s2, off);
  }
  const float mu = s / DIM;
  const float rs = rsqrtf(s2 / DIM - mu * mu + LN_EPS);
#pragma unroll
  for (int c = 0; c < 4; c++) {
    float4 g = ((const float4*)gamma)[c * 64 + lane];
    float4 b = ((const float4*)beta)[c * 64 + lane];
    union { f16 h[4]; uint2 u; } o;
    o.h[0] = (f16)((x[c].x - mu) * rs * g.x + b.x);
    o.h[1] = (f16)((x[c].y - mu) * rs * g.y + b.y);
    o.h[2] = (f16)((x[c].z - mu) * rs * g.z + b.z);
    o.h[3] = (f16)((x[c].w - mu) * rs * g.w + b.w);
    ((uint2*)(a_h + (size_t)row * DIM))[c * 64 + lane] = o.u;
  }
}

// ---------------------------------------------------------------------------
// K0b: transpose + fp16 convert of W_in and W_out (1024x1024 each).
// ---------------------------------------------------------------------------
__global__ void __launch_bounds__(256) transpose_f16(
    const float* __restrict__ W0, const float* __restrict__ W1,
    f16* __restrict__ T0, f16* __restrict__ T1) {
  const float* W = blockIdx.z ? W1 : W0;
  f16* T = blockIdx.z ? T1 : T0;
  __shared__ float tile[32][33];
  int tx = threadIdx.x & 31, ty = threadIdx.x >> 5;
  int k0 = blockIdx.x * 32, n0 = blockIdx.y * 32;
#pragma unroll
  for (int i = 0; i < 4; i++)
    tile[ty + 8 * i][tx] = W[(size_t)(k0 + ty + 8 * i) * DIM + n0 + tx];
  __syncthreads();
#pragma unroll
  for (int i = 0; i < 4; i++)
    T[(size_t)(n0 + ty + 8 * i) * DIM + k0 + tx] = (f16)tile[tx][ty + 8 * i];
}

// ---------------------------------------------------------------------------
// K1: projection GEMM, 320x256 tile -> grid 256 blocks = 1 per CU.
//     ONE phase per K-tile-64 (16 phases, 32 barriers total).
//
//   f[RTOT x 1024] = a_h[RTOT x 1024] @ wt_in^T; q/k rows pre-normalized
//   per head (wave's 64-col span is exactly one head).
//
// Geometry: 8 waves (2M x 4N); per-wave 160x64 out, acc[10][4] f32x4.
// LDS 144 KiB: A 2 tile-bufs x [320][64], B 2 x [256][64], f16.
// Chunk swizzle: 16B chunk c' = (half*4+slot) ^ (row&7) applied to BOTH
// the staging source address and the ds_read address (2 lanes/bank, free).
//
// Per-tile phase t (buf b = t&1), merged both K-halves:
//   STAGE_A(t+1 -> b^1) + STAGE_B(t+1 -> b^1)   [9 async16]
//   vmcnt(9)   [outstanding 18 -> drains exactly tile t's 9]
//   s_barrier
//   half0: 4 bf + 10 af ds_read_b128, 40 MFMA
//   half1: 4 bf + 10 af ds_read_b128, 40 MFMA   (regs reused, ~230 VGPR)
//   s_barrier
// Race-freedom: the stage targets buf^1 whose LAST ds_read completed
// before the end barrier of phase t-1 (entire buffer freed at tile
// granularity); overwrite data lands >=900cy after stage issue, well
// after those reads retired. Stage->consume distance = 1 phase
// (~3900cy >> 900cy HBM). Prologue drains tile 0 (vmcnt(0)); last
// phase has no stage and waits vmcnt(0).
//
// Epilogue: acc -> LDS scratch -> 16B-contiguous stores (full 64B lines,
// keeps WRITE_SIZE at the ideal 40 MB).
// ---------------------------------------------------------------------------
constexpr int PT_A = 320 * 64;   // f16 per A tile buffer (20480)
constexpr int PT_B = 256 * 64;   // f16 per B tile buffer (16384)

#define STAGE_A(buf, kt) do {                                        \
    const f16* s_ = gA + (size_t)(kt) * 64;                          \
    f16* d_ = AsW + (buf) * PT_A;                                    \
    async16(s_,          d_);                                        \
    async16(s_ +  65536, d_ + 4096);                                 \
    async16(s_ + 131072, d_ + 8192);                                 \
    async16(s_ + 196608, d_ + 12288);                                \
    async16(s_ + 262144, d_ + 16384);                                \
  } while (0)

#define STAGE_B(buf, kt) do {                                        \
    const f16* s_ = gB + (size_t)(kt) * 64;                          \
    f16* d_ = BsW + (buf) * PT_B;                                    \
    async16(s_,          d_);                                        \
    async16(s_ +  65536, d_ + 4096);                                 \
    async16(s_ + 131072, d_ + 8192);                                 \
    async16(s_ + 196608, d_ + 12288);                                \
  } while (0)

#define STAGE_AB(buf, kt) do { STAGE_A(buf, kt); STAGE_B(buf, kt); } while (0)

#define WT9 asm volatile("s_waitcnt vmcnt(9)" ::: "memory")
#define WT0 asm volatile("s_waitcnt vmcnt(0)" ::: "memory")
#define STN ((void)0)

#define HALF(BUF, H)                                                 \
    _Pragma("unroll") for (int j_ = 0; j_ < 4; ++j_)                 \
      bf[j_] = *(const f16x8*)(bB##H + (BUF) * PT_B + j_ * 1024);    \
    _Pragma("unroll") for (int f_ = 0; f_ < 5; ++f_)                 \
      af0[f_] = *(const f16x8*)(aB##H + (BUF) * PT_A + f_ * 1024);   \
    _Pragma("unroll") for (int f_ = 0; f_ < 5; ++f_)                 \
      af1[f_] = *(const f16x8*)(aB##H + (BUF) * PT_A + 5120 +        \
                                f_ * 1024);                          \
    __builtin_amdgcn_s_setprio(1);                                   \
    _Pragma("unroll") for (int f_ = 0; f_ < 5; ++f_)                 \
      _Pragma("unroll") for (int j_ = 0; j_ < 4; ++j_)               \
        acc[f_][j_] = __builtin_amdgcn_mfma_f32_16x16x32_f16(        \
            af0[f_], bf[j_], acc[f_][j_], 0, 0, 0);                  \
    _Pragma("unroll") for (int f_ = 0; f_ < 5; ++f_)                 \
      _Pragma("unroll") for (int j_ = 0; j_ < 4; ++j_)               \
        acc[5 + f_][j_] = __builtin_amdgcn_mfma_f32_16x16x32_f16(    \
            af1[f_], bf[j_], acc[5 + f_][j_], 0, 0, 0);              \
    __builtin_amdgcn_s_setprio(0);

#define PHT(BUF, STG, WT) {                                          \
    STG;                                                             \
    __builtin_amdgcn_sched_barrier(0);                               \
    WT;                                                              \
    __builtin_amdgcn_s_barrier();                                    \
    __builtin_amdgcn_sched_barrier(0);                               \
    HALF(BUF, 0)                                                     \
    HALF(BUF, 1)                                                     \
    __builtin_amdgcn_sched_barrier(0);                               \
    __builtin_amdgcn_s_barrier();                                    \
  }

__global__ void __launch_bounds__(512, 2) proj_gemm(
    const f16* __restrict__ A, const f16* __restrict__ Bt,
    f16* __restrict__ C) {
  __shared__ __align__(16) f16 As[2 * PT_A];   // 80 KB
  __shared__ __align__(16) f16 Bs[2 * PT_B];   // 64 KB

  const int tid = threadIdx.x;
  const int wid = tid >> 6;
  const int lane = tid & 63;
  const int la15 = lane & 15;

  // bijective XCD swizzle (256 % 8 == 0); col-tile fastest within an XCD
  // chunk so a row-panel's 4 column tiles share one XCD's L2.
  const int bid = blockIdx.x;
  const int swz = (bid & 7) * 32 + (bid >> 3);
  const int row0 = (swz >> 2) * 320;
  const int col0 = (swz & 3) * 256;

  const int wm = (wid >> 2) * 160;      // warp_m in {0,1}
  const int wn = (wid & 3) * 64;        // warp_n in {0..3}

  // ---- staging source (per-thread), chunk-XOR pre-applied to source ----
  const int hs = (tid & 7) ^ ((tid >> 3) & 7);
  const f16* gA = A + (size_t)(row0 + (tid >> 3)) * DIM + (hs >> 2) * 32 +
                  (hs & 3) * 8;
  const f16* gB = Bt + (size_t)(col0 + (tid >> 3)) * DIM + (hs >> 2) * 32 +
                  (hs & 3) * 8;
  f16* AsW = As + wid * 512;            // wave-uniform LDS dest bases
  f16* BsW = Bs + wid * 512;

  // ---- fragment read bases (per half), XOR folded per-thread ----
  const int g = lane >> 4;
  const int r7 = la15 & 7;
  const int cs0 = (g ^ r7) * 8;             // half 0 chunk
  const int cs1 = ((4 + g) ^ r7) * 8;       // half 1 chunk
  const f16* aB0 = As + (wm + la15) * 64 + cs0;
  const f16* aB1 = As + (wm + la15) * 64 + cs1;
  const f16* bB0 = Bs + (wn + la15) * 64 + cs0;
  const f16* bB1 = Bs + (wn + la15) * 64 + cs1;

  f32x4 acc[10][4];
#pragma unroll
  for (int i = 0; i < 10; i++)
#pragma unroll
    for (int j = 0; j < 4; j++) acc[i][j] = (f32x4){0.f, 0.f, 0.f, 0.f};
  f16x8 af0[5], af1[5], bf[4];

  // prologue: tile 0 into buf0, drain fully
  STAGE_AB(0, 0);
  __builtin_amdgcn_sched_barrier(0);
  WT0;
  __builtin_amdgcn_s_barrier();
  __builtin_amdgcn_sched_barrier(0);

#pragma unroll 1
  for (int it = 0; it < 7; ++it) {
    const int t1 = 2 * it + 1, t2 = 2 * it + 2;
    PHT(0, STAGE_AB(1, t1), WT9)   // compute tile 2it   (buf0), stage t1
    PHT(1, STAGE_AB(0, t2), WT9)   // compute tile 2it+1 (buf1), stage t2
  }
  PHT(0, STAGE_AB(1, 15), WT9)     // compute tile 14 (buf0), stage 15
  PHT(1, STN,             WT0)     // compute tile 15 (buf1)

  // ---- per-head normalization (per-element row predicate: BM=320 blocks
  //      can straddle the k/v boundary at row 12288) ----
  const int crow = (lane >> 4) * 4;
#pragma unroll
  for (int mh = 0; mh < 2; ++mh)
#pragma unroll
    for (int f = 0; f < 5; ++f) {
      const int m = mh * 5 + f;
      const int rbase = row0 + wm + mh * 80 + f * 16 + crow;
#pragma unroll
      for (int r = 0; r < 4; ++r) {
        float s = acc[m][0][r] * acc[m][0][r] + acc[m][1][r] * acc[m][1][r]
                + acc[m][2][r] * acc[m][2][r] + acc[m][3][r] * acc[m][3][r];
        s += __shfl_xor(s, 1);
        s += __shfl_xor(s, 2);
        s += __shfl_xor(s, 4);
        s += __shfl_xor(s, 8);
        if (rbase + r < RQ + RK) {
          const float inv = rsqrtf(s);
#pragma unroll
          for (int j = 0; j < 4; ++j) acc[m][j][r] *= inv;
        }
      }
    }

  // ---- epilogue: LDS-transpose to full-line 16B-contiguous stores ----
  // scratch overlays As: [2 halves][16 rows][264 cols] f16 (16.9 KB)
  f16* sc = As;
  const int wmi = wid >> 2;
  const int ehalf = tid >> 8;
  const int err = (tid >> 4) & 15;
  const int ecc = tid & 15;
  const f16* rb_l = sc + ehalf * (16 * 264) + err * 264 + ecc * 16;
#pragma unroll
  for (int mh = 0; mh < 2; ++mh)
#pragma unroll
    for (int f = 0; f < 5; ++f) {
      const int m = mh * 5 + f;
#pragma unroll
      for (int j = 0; j < 4; ++j)
#pragma unroll
        for (int r = 0; r < 4; ++r)
          sc[wmi * (16 * 264) + (crow + r) * 264 + wn + j * 16 + la15] =
              (f16)acc[m][j][r];
      __syncthreads();
      f16x8 v0 = *(const f16x8*)(rb_l);
      f16x8 v1 = *(const f16x8*)(rb_l + 8);
      const int grow = row0 + ehalf * 160 + mh * 80 + f * 16 + err;
      f16* Cp = C + (size_t)grow * DIM + col0 + ecc * 16;
      *(f16x8*)(Cp) = v0;
      *(f16x8*)(Cp + 8) = v1;
      if (!(mh == 1 && f == 4)) __syncthreads();
    }
}

// ---------------------------------------------------------------------------
// MFMA fp16 GEMM (kept for the final GEMM, MT=64 path).
// ---------------------------------------------------------------------------
template <int MT, bool OUT_F16, bool NORMS, bool BIAS, bool PERB>
__global__ void __launch_bounds__(256) mfma_gemm(
    const f16* __restrict__ A, const f16* __restrict__ Bt,
    void* __restrict__ Cout, const float* __restrict__ bias) {
  constexpr int JT = (MT == 128) ? 4 : 2;
  __shared__ f16 Asl[2][MT * 32];
  __shared__ f16 Bsl[2][128 * 32];
  const int t = threadIdx.x;
  const int wid = t >> 6;
  const int lane = t & 63;
  const int row0 = blockIdx.x * MT;
  const int col0 = blockIdx.y * 128;
  const int wm = (MT == 128) ? (wid >> 1) * 64 : 0;
  const int wn = (MT == 128) ? (wid & 1) * 64 : wid * 32;

  const f16* BtB = PERB ? Bt + (size_t)(row0 >> 10) * DIM * DIM : Bt;

  const int rB = 32 * wid + (lane >> 2);
  const int qB = ((lane & 3) - ((rB >> 1) & 3)) & 3;
  const f16* gB = BtB + (size_t)(col0 + rB) * DIM + qB * 8;
  f16* lB0 = Bsl[0] + 32 * wid * 32;
  f16* lB1 = Bsl[1] + 32 * wid * 32;
  const int rA = (MT == 128 ? 32 : 16) * wid + (lane >> 2);
  const int qA = ((lane & 3) - ((rA >> 1) & 3)) & 3;
  const f16* gA = A + (size_t)(row0 + rA) * DIM + qA * 8;
  f16* lA0 = Asl[0] + (MT == 128 ? 32 : 16) * wid * 32;
  f16* lA1 = Asl[1] + (MT == 128 ? 32 : 16) * wid * 32;

  f32x4 acc[4][JT];
#pragma unroll
  for (int i = 0; i < 4; i++)
#pragma unroll
    for (int j = 0; j < JT; j++) acc[i][j] = (f32x4){0.f, 0.f, 0.f, 0.f};

  const int mrow = lane & 15;
  const int kq_p = (((lane >> 4) + ((lane >> 1) & 3)) & 3) * 8;

  for (int kt = 0; kt < DIM / 64; ++kt) {
    if (kt) __syncthreads();
    const int ko = kt * 64;
    async16(gA + ko,      lA0);
    if (MT == 128) async16(gA + ko + 16 * DIM, lA0 + 512);
    async16(gB + ko,      lB0);
    async16(gB + ko + 16 * DIM, lB0 + 512);
    async16(gA + ko + 32, lA1);
    if (MT == 128) async16(gA + ko + 32 + 16 * DIM, lA1 + 512);
    async16(gB + ko + 32, lB1);
    async16(gB + ko + 32 + 16 * DIM, lB1 + 512);
    __syncthreads();

#pragma unroll
    for (int h = 0; h < 2; ++h) {
      f16x8 af[4], bf[JT];
#pragma unroll
      for (int i = 0; i < 4; i++)
        af[i] = *(const f16x8*)(Asl[h] + (wm + i * 16 + mrow) * 32 + kq_p);
#pragma unroll
      for (int j = 0; j < JT; j++)
        bf[j] = *(const f16x8*)(Bsl[h] + (wn + j * 16 + mrow) * 32 + kq_p);
#pragma unroll
      for (int i = 0; i < 4; i++)
#pragma unroll
        for (int j = 0; j < JT; j++)
          acc[i][j] = __builtin_amdgcn_mfma_f32_16x16x32_f16(af[i], bf[j], acc[i][j], 0, 0, 0);
    }
  }

  if (NORMS && MT == 128) {
    if (row0 < RQ + RK) {
      float sums[4][4];
#pragma unroll
      for (int i = 0; i < 4; i++)
#pragma unroll
        for (int r = 0; r < 4; r++) {
          float s = 0.f;
#pragma unroll
          for (int j = 0; j < JT; j++) s += acc[i][j][r] * acc[i][j][r];
          sums[i][r] = s;
        }
#pragma unroll
      for (int off = 1; off < 16; off <<= 1)
#pragma unroll
        for (int i = 0; i < 4; i++)
#pragma unroll
          for (int r = 0; r < 4; r++)
            sums[i][r] += __shfl_xor(sums[i][r], off);
#pragma unroll
      for (int i = 0; i < 4; i++)
#pragma unroll
        for (int r = 0; r < 4; r++) {
          const float inv = rsqrtf(sums[i][r]);
#pragma unroll
          for (int j = 0; j < JT; j++) acc[i][j][r] *= inv;
        }
    }
  }

  const int ccol = lane & 15;
  const int crow = (lane >> 4) * 4;
  if (OUT_F16) {
    f16* C = (f16*)Cout;
#pragma unroll
    for (int j = 0; j < JT; j++) {
      const int col = col0 + wn + j * 16 + ccol;
#pragma unroll
      for (int i = 0; i < 4; i++) {
        f16* Cp = C + (size_t)(row0 + wm + i * 16 + crow) * DIM + col;
#pragma unroll
        for (int r = 0; r < 4; r++) Cp[(size_t)r * DIM] = (f16)acc[i][j][r];
      }
    }
  } else {
    float* C = (float*)Cout;
#pragma unroll
    for (int j = 0; j < JT; j++) {
      const int col = col0 + wn + j * 16 + ccol;
      float bv = BIAS ? bias[col] : 0.f;
#pragma unroll
      for (int i = 0; i < 4; i++) {
        float* Cp = C + (size_t)(row0 + wm + i * 16 + crow) * DIM + col;
#pragma unroll
        for (int r = 0; r < 4; r++) Cp[(size_t)r * DIM] = acc[i][j][r] + bv;
      }
    }
  }
}

// ---------------------------------------------------------------------------
// K3: per-(slice,b,h) partial S = sum over 256 m of g_k[m] outer f_v[m].
// ---------------------------------------------------------------------------
__global__ void __launch_bounds__(256) s_kernel(
    const f16* __restrict__ f, float* __restrict__ S4) {
  const int bh = blockIdx.x;
  const int b = bh >> 4, h = bh & 15;
  const int mbase = blockIdx.y * (SEQK / NSLC);
  const int t = threadIdx.x;
  __shared__ float ks[32][68];
  __shared__ float vs[32][68];
  const int lm   = t >> 3;
  const int lseg = (t & 7) * 8;
  const int d1 = (t & 15) * 4;
  const int d2 = (t >> 4) * 4;
  float acc[4][4] = {{0.f}};
  const f16* fk_base = f + ((size_t)RQ + (size_t)b * SEQK) * DIM + h * DH;
  const f16* fv_base = f + ((size_t)RQ + RK + (size_t)b * SEQK) * DIM + h * DH;

  int m = mbase + lm;
  f16x8 kv = *(const f16x8*)(fk_base + (size_t)m * DIM + lseg);
  f16x8 vv = *(const f16x8*)(fv_base + (size_t)m * DIM + lseg);

  constexpr int SUBS = SEQK / NSLC / 32;  // 8
  for (int sub = 0; sub < SUBS; ++sub) {
    __syncthreads();
#pragma unroll
    for (int e = 0; e < 8; e++) {
      ks[lm][lseg + e] = (float)kv[e];
      vs[lm][lseg + e] = (float)vv[e];
    }
    __syncthreads();
    if (sub + 1 < SUBS) {
      m = mbase + (sub + 1) * 32 + lm;
      kv = *(const f16x8*)(fk_base + (size_t)m * DIM + lseg);
      vv = *(const f16x8*)(fv_base + (size_t)m * DIM + lseg);
    }
#pragma unroll
    for (int mm = 0; mm < 32; ++mm) {
      float4 kk = *(const float4*)&ks[mm][d1];
      float4 vv2 = *(const float4*)&vs[mm][d2];
      acc[0][0] = fmaf(kk.x, vv2.x, acc[0][0]);
      acc[0][1] = fmaf(kk.x, vv2.y, acc[0][1]);
      acc[0][2] = fmaf(kk.x, vv2.z, acc[0][2]);
      acc[0][3] = fmaf(kk.x, vv2.w, acc[0][3]);
      acc[1][0] = fmaf(kk.y, vv2.x, acc[1][0]);
      acc[1][1] = fmaf(kk.y, vv2.y, acc[1][1]);
      acc[1][2] = fmaf(kk.y, vv2.z, acc[1][2]);
      acc[1][3] = fmaf(kk.y, vv2.w, acc[1][3]);
      acc[2][0] = fmaf(kk.z, vv2.x, acc[2][0]);
      acc[2][1] = fmaf(kk.z, vv2.y, acc[2][1]);
      acc[2][2] = fmaf(kk.z, vv2.z, acc[2][2]);
      acc[2][3] = fmaf(kk.z, vv2.w, acc[2][3]);
      acc[3][0] = fmaf(kk.w, vv2.x, acc[3][0]);
      acc[3][1] = fmaf(kk.w, vv2.y, acc[3][1]);
      acc[3][2] = fmaf(kk.w, vv2.z, acc[3][2]);
      acc[3][3] = fmaf(kk.w, vv2.w, acc[3][3]);
    }
  }
  float* Sp = S4 + ((size_t)blockIdx.y * BH + bh) * DH * DH;
#pragma unroll
  for (int i = 0; i < 4; i++)
#pragma unroll
    for (int j = 0; j < 4; j++)
      Sp[(d1 + i) * DH + (d2 + j)] = acc[i][j];
}

// ---------------------------------------------------------------------------
// K3b: sum the NSLC partial S slices -> Sh fp16 [bh][d1][d2] row-major.
// ---------------------------------------------------------------------------
__global__ void __launch_bounds__(256) s_reduce(
    const float* __restrict__ S4, f16* __restrict__ Sh) {
  const int bh = blockIdx.x;
  const int t = threadIdx.x;
  const size_t base = (size_t)bh * DH * DH + t * 16;
  constexpr size_t STR = (size_t)BH * DH * DH;
#pragma unroll
  for (int c = 0; c < 4; c++) {
    float4 s = {0.f, 0.f, 0.f, 0.f};
#pragma unroll
    for (int p = 0; p < NSLC; p++) {
      float4 sp = *(const float4*)(S4 + base + p * STR + 4 * c);
      s.x += sp.x; s.y += sp.y; s.z += sp.z; s.w += sp.w;
    }
    union { f16 h[4]; uint2 u; } o;
    o.h[0] = (f16)s.x; o.h[1] = (f16)s.y; o.h[2] = (f16)s.z; o.h[3] = (f16)s.w;
    *(uint2*)(Sh + base + 4 * c) = o.u;
  }
}

// ---------------------------------------------------------------------------
// K3c: Mt[b][n][64h+d1] = sum_d2 wt_out[n][64h+d2] * Sh[b,h][d1][d2]
// ---------------------------------------------------------------------------
__global__ void __launch_bounds__(256) m_build(
    const f16* __restrict__ wt_out, const f16* __restrict__ Sh,
    f16* __restrict__ Mt) {
  const int n0 = blockIdx.x * 128;
  const int bh = blockIdx.y;
  const int b = bh >> 4, h = bh & 15;
  __shared__ f16 Asl[128 * 64];
  __shared__ f16 Bsl[64 * 64];
  const int t = threadIdx.x;
  const int wid = t >> 6, lane = t & 63;

  const f16* gA = wt_out + (size_t)(n0 + 32 * wid + (lane >> 3)) * DIM
                  + 64 * h + (lane & 7) * 8;
  f16* lA = Asl + 32 * wid * 64;
  const f16* gB = Sh + (size_t)bh * DH * DH + (16 * wid + (lane >> 3)) * 64
                  + (lane & 7) * 8;
  f16* lB = Bsl + 16 * wid * 64;
#pragma unroll
  for (int o = 0; o < 4; o++) async16(gA + (size_t)(8 * o) * DIM, lA + 8 * o * 64);
  async16(gB, lB);
  async16(gB + 8 * 64, lB + 8 * 64);
  __syncthreads();

  const int wm = (wid >> 1) * 64;
  const int wn = (wid & 1) * 32;
  const int mrow = lane & 15;
  f32x4 acc[4][2];
#pragma unroll
  for (int i = 0; i < 4; i++)
#pragma unroll
    for (int j = 0; j < 2; j++) acc[i][j] = (f32x4){0.f, 0.f, 0.f, 0.f};

#pragma unroll
  for (int kh = 0; kh < 2; kh++) {
    const int kq = kh * 32 + (lane >> 4) * 8;
    f16x8 af[4], bf[2];
#pragma unroll
    for (int i = 0; i < 4; i++)
      af[i] = *(const f16x8*)(Asl + (wm + i * 16 + mrow) * 64 + kq);
#pragma unroll
    for (int j = 0; j < 2; j++)
      bf[j] = *(const f16x8*)(Bsl + (wn + j * 16 + mrow) * 64 + kq);
#pragma unroll
    for (int i = 0; i < 4; i++)
#pragma unroll
      for (int j = 0; j < 2; j++)
        acc[i][j] = __builtin_amdgcn_mfma_f32_16x16x32_f16(af[i], bf[j], acc[i][j], 0, 0, 0);
  }

  const int ccol = lane & 15;
  const int crow = (lane >> 4) * 4;
  f16* Mb = Mt + (size_t)b * DIM * DIM;
#pragma unroll
  for (int j = 0; j < 2; j++) {
    const int col = 64 * h + wn + j * 16 + ccol;
#pragma unroll
    for (int i = 0; i < 4; i++) {
      f16* Mp = Mb + (size_t)(n0 + wm + i * 16 + crow) * DIM + col;
#pragma unroll
      for (int r = 0; r < 4; r++) Mp[(size_t)r * DIM] = (f16)acc[i][j][r];
    }
  }
}

// ---------------------------------------------------------------------------
extern "C" void kernel_launch(void* const* d_in, const int* in_sizes, int n_in,
                              void* d_out, int out_size, void* d_ws, size_t ws_size,
                              hipStream_t stream) {
  const float* q     = (const float*)d_in[0];
  const float* k     = (const float*)d_in[1];
  const float* v     = (const float*)d_in[2];
  const float* gamma = (const float*)d_in[3];
  const float* beta  = (const float*)d_in[4];
  const float* W_in  = (const float*)d_in[5];
  const float* W_out = (const float*)d_in[6];
  const float* b_out = (const float*)d_in[7];
  float* out = (float*)d_out;

  // workspace layout
  char* w = (char*)d_ws;
  f16*   f      = (f16*)w;                                     // 40 MB
  f16*   a_h    = f + (size_t)RTOT * DIM;                      // 40 MB
  f16*   wt_in  = a_h + (size_t)RTOT * DIM;                    // 2 MB
  f16*   wt_out = wt_in + (size_t)DIM * DIM;                   // 2 MB
  f16*   Mt     = wt_out + (size_t)DIM * DIM;                  // 8 MB
  f16*   Sh     = Mt + (size_t)BATCH * DIM * DIM;              // 512 KB
  float* S4     = (float*)(Sh + (size_t)BH * DH * DH);         // 8 MB

  ln_to_f16<<<RTOT / 4, 256, 0, stream>>>(q, k, v, gamma, beta, a_h);
  transpose_f16<<<dim3(DIM / 32, DIM / 32, 2), 256, 0, stream>>>(
      W_in, W_out, wt_in, wt_out);

  // f = LN(t) @ W_in for all rows; q/k rows pre-normalized per head
  proj_gemm<<<dim3(256), 512, 0, stream>>>(a_h, wt_in, f);

  s_kernel<<<dim3(BH, NSLC), 256, 0, stream>>>(f, S4);

  s_reduce<<<BH, 256, 0, stream>>>(S4, Sh);

  m_build<<<dim3(DIM / 128, BH), 256, 0, stream>>>(wt_out, Sh, Mt);

  // out = g_q @ Mt[b]^T + b_out (per-batch weights)
  mfma_gemm<64, false, false, true, true>
      <<<dim3(RQ / 64, DIM / 128), 256, 0, stream>>>(f, Mt, out, b_out);
}

// Round 5
// 230.058 us; speedup vs baseline: 1.0856x; 1.0070x over previous
//
#include <hip/hip_runtime.h>

// Problem constants
constexpr int BATCH = 4;
constexpr int SEQQ  = 1024;
constexpr int SEQK  = 2048;
constexpr int DIM   = 1024;
constexpr int NH    = 16;
constexpr int DH    = 64;
constexpr int RQ    = BATCH * SEQQ;          // 4096 q rows
constexpr int RK    = BATCH * SEQK;          // 8192 k rows (== v rows)
constexpr int RTOT  = RQ + 2 * RK;           // 20480
constexpr int BH    = BATCH * NH;            // 64
constexpr int NSLC  = 8;                     // s_kernel K-slices
constexpr float LN_EPS = 1e-5f;

typedef _Float16 f16;
typedef __attribute__((ext_vector_type(8))) _Float16 f16x8;
typedef __attribute__((ext_vector_type(4))) float f32x4;

__device__ __forceinline__ void async16(const void* g, void* l) {
  __builtin_amdgcn_global_load_lds(
      (const __attribute__((address_space(1))) void*)g,
      (__attribute__((address_space(3))) void*)l, 16, 0, 0);
}

// ---------------------------------------------------------------------------
// K0: fused LayerNorm -> fp16. One wave per row (no LDS, no barriers).
// ---------------------------------------------------------------------------
__global__ void __launch_bounds__(256) ln_to_f16(
    const float* __restrict__ q, const float* __restrict__ k,
    const float* __restrict__ v, const float* __restrict__ gamma,
    const float* __restrict__ beta, f16* __restrict__ a_h) {
  const int row = blockIdx.x * 4 + (threadIdx.x >> 6);
  const int lane = threadIdx.x & 63;
  const float* src;
  if (row < RQ)            src = q + (size_t)row * DIM;
  else if (row < RQ + RK)  src = k + (size_t)(row - RQ) * DIM;
  else                     src = v + (size_t)(row - RQ - RK) * DIM;
  float4 x[4];
  float s = 0.f, s2 = 0.f;
#pragma unroll
  for (int c = 0; c < 4; c++) {
    x[c] = ((const float4*)src)[c * 64 + lane];
    s  += x[c].x + x[c].y + x[c].z + x[c].w;
    s2 += x[c].x * x[c].x + x[c].y * x[c].y + x[c].z * x[c].z + x[c].w * x[c].w;
  }
#pragma unroll
  for (int off = 1; off < 64; off <<= 1) {
    s  += __shfl_xor(s, off);
    s2 += __shfl_xor(s2, off);
  }
  const float mu = s / DIM;
  const float rs = rsqrtf(s2 / DIM - mu * mu + LN_EPS);
#pragma unroll
  for (int c = 0; c < 4; c++) {
    float4 g = ((const float4*)gamma)[c * 64 + lane];
    float4 b = ((const float4*)beta)[c * 64 + lane];
    union { f16 h[4]; uint2 u; } o;
    o.h[0] = (f16)((x[c].x - mu) * rs * g.x + b.x);
    o.h[1] = (f16)((x[c].y - mu) * rs * g.y + b.y);
    o.h[2] = (f16)((x[c].z - mu) * rs * g.z + b.z);
    o.h[3] = (f16)((x[c].w - mu) * rs * g.w + b.w);
    ((uint2*)(a_h + (size_t)row * DIM))[c * 64 + lane] = o.u;
  }
}

// ---------------------------------------------------------------------------
// K0b: transpose + fp16 convert of W_in and W_out (1024x1024 each).
// ---------------------------------------------------------------------------
__global__ void __launch_bounds__(256) transpose_f16(
    const float* __restrict__ W0, const float* __restrict__ W1,
    f16* __restrict__ T0, f16* __restrict__ T1) {
  const float* W = blockIdx.z ? W1 : W0;
  f16* T = blockIdx.z ? T1 : T0;
  __shared__ float tile[32][33];
  int tx = threadIdx.x & 31, ty = threadIdx.x >> 5;
  int k0 = blockIdx.x * 32, n0 = blockIdx.y * 32;
#pragma unroll
  for (int i = 0; i < 4; i++)
    tile[ty + 8 * i][tx] = W[(size_t)(k0 + ty + 8 * i) * DIM + n0 + tx];
  __syncthreads();
#pragma unroll
  for (int i = 0; i < 4; i++)
    T[(size_t)(n0 + ty + 8 * i) * DIM + k0 + tx] = (f16)tile[tx][ty + 8 * i];
}

// ---------------------------------------------------------------------------
// K1: projection GEMM, 320x256 tile -> grid 256 blocks = 1 per CU.
//     Fine-grained sub-phase schedule (reads-BEFORE-barrier, R1-style).
//
//   f[RTOT x 1024] = a_h[RTOT x 1024] @ wt_in^T; q/k rows pre-normalized
//   per head (wave's 64-col span is exactly one head).
//
// Geometry: 8 waves (2M x 4N); per-wave 160x64 out, acc[10][4] f32x4.
// LDS 144 KiB: A 2 tile-bufs x [320][64], B 2 x [256][64], f16.
// Chunk swizzle: 16B chunk c' = (half*4+slot) ^ (row&7) applied to BOTH
// the staging source address and the ds_read address (2 lanes/bank, free).
//
// Per K-tile t (buf p = t&1): 4 sub-phases (H,MH) of 20 MFMA each:
//   SP0 (H0,MH0): rd bf_h0[4]+af[5];  STAGE_A(t+1->p^1)
//   SP1 (H0,MH1): rd af[5];           STAGE_B(t+1->p^1)
//   SP2 (H1,MH0): rd bf_h1[4]+af[5]
//   SP3 (H1,MH1): rd af[5];           vmcnt(0)   [drains t+1's 9 DMA]
// Each sub-phase: {reads ; stage} -> s_barrier -> lgkmcnt(0)+sched_barrier
// -> setprio(1) 20 MFMA setprio(0) -> s_barrier.
// KEY: reads are issued BEFORE the top barrier, so their latency overlaps
// barrier convergence and the staggered lgkmcnt release de-synchronizes
// waves (one wave's MFMA overlaps another's LDS reads). Reads of buf p at
// a sub-phase top target data vmcnt-drained >=2 barriers earlier (safe);
// buf p's next overwrite is staged at tile t+2's SP0, after tile t's end
// barrier (safe). bf persists across the two MH sub-phases of a half.
//
// Epilogue: acc -> LDS scratch -> 16B-contiguous stores (full 64B lines,
// keeps WRITE_SIZE at the ideal 40 MB).
// ---------------------------------------------------------------------------
constexpr int PT_A = 320 * 64;   // f16 per A tile buffer (20480)
constexpr int PT_B = 256 * 64;   // f16 per B tile buffer (16384)

#define STAGE_A(buf, kt) do {                                        \
    const f16* s_ = gA + (size_t)(kt) * 64;                          \
    f16* d_ = AsW + (buf) * PT_A;                                    \
    async16(s_,          d_);                                        \
    async16(s_ +  65536, d_ + 4096);                                 \
    async16(s_ + 131072, d_ + 8192);                                 \
    async16(s_ + 196608, d_ + 12288);                                \
    async16(s_ + 262144, d_ + 16384);                                \
  } while (0)

#define STAGE_B(buf, kt) do {                                        \
    const f16* s_ = gB + (size_t)(kt) * 64;                          \
    f16* d_ = BsW + (buf) * PT_B;                                    \
    async16(s_,          d_);                                        \
    async16(s_ +  65536, d_ + 4096);                                 \
    async16(s_ + 131072, d_ + 8192);                                 \
    async16(s_ + 196608, d_ + 12288);                                \
  } while (0)

#define STAGE_AB(buf, kt) do { STAGE_A(buf, kt); STAGE_B(buf, kt); } while (0)

#define WT0 asm volatile("s_waitcnt vmcnt(0)" ::: "memory")
#define WTN ((void)0)
#define STN ((void)0)

#define RDBF(H, BUF)                                                 \
    _Pragma("unroll") for (int j_ = 0; j_ < 4; ++j_)                 \
      bf[j_] = *(const f16x8*)(bB##H + (BUF) * PT_B + j_ * 1024)

#define RDAF(H, MH, BUF)                                             \
    _Pragma("unroll") for (int f_ = 0; f_ < 5; ++f_)                 \
      af[f_] = *(const f16x8*)(aB##H + (BUF) * PT_A + (MH) * 5120 +  \
                               f_ * 1024)

#define SUBPH(RDS, STG, WT, MH)                                      \
  {                                                                  \
    RDS;                                                             \
    STG;                                                             \
    __builtin_amdgcn_sched_barrier(0);                               \
    WT;                                                              \
    __builtin_amdgcn_s_barrier();                                    \
    __builtin_amdgcn_sched_barrier(0);                               \
    asm volatile("s_waitcnt lgkmcnt(0)" ::: "memory");               \
    __builtin_amdgcn_sched_barrier(0);                               \
    __builtin_amdgcn_s_setprio(1);                                   \
    _Pragma("unroll") for (int f_ = 0; f_ < 5; ++f_)                 \
      _Pragma("unroll") for (int j_ = 0; j_ < 4; ++j_)               \
        acc[(MH) * 5 + f_][j_] = __builtin_amdgcn_mfma_f32_16x16x32_f16( \
            af[f_], bf[j_], acc[(MH) * 5 + f_][j_], 0, 0, 0);        \
    __builtin_amdgcn_s_setprio(0);                                   \
    __builtin_amdgcn_sched_barrier(0);                               \
    __builtin_amdgcn_s_barrier();                                    \
  }

#define TILE(BUF, STGA, STGB, WTL)                                   \
  SUBPH({ RDBF(0, BUF); RDAF(0, 0, BUF); }, STGA, WTN, 0)            \
  SUBPH({ RDAF(0, 1, BUF); },               STGB, WTN, 1)            \
  SUBPH({ RDBF(1, BUF); RDAF(1, 0, BUF); }, STN,  WTN, 0)            \
  SUBPH({ RDAF(1, 1, BUF); },               STN,  WTL, 1)

__global__ void __launch_bounds__(512, 2) proj_gemm(
    const f16* __restrict__ A, const f16* __restrict__ Bt,
    f16* __restrict__ C) {
  __shared__ __align__(16) f16 As[2 * PT_A];   // 80 KB
  __shared__ __align__(16) f16 Bs[2 * PT_B];   // 64 KB

  const int tid = threadIdx.x;
  const int wid = tid >> 6;
  const int lane = tid & 63;
  const int la15 = lane & 15;

  // bijective XCD swizzle (256 % 8 == 0); col-tile fastest within an XCD
  // chunk so a row-panel's 4 column tiles share one XCD's L2.
  const int bid = blockIdx.x;
  const int swz = (bid & 7) * 32 + (bid >> 3);
  const int row0 = (swz >> 2) * 320;
  const int col0 = (swz & 3) * 256;

  const int wm = (wid >> 2) * 160;      // warp_m in {0,1}
  const int wn = (wid & 3) * 64;        // warp_n in {0..3}

  // ---- staging source (per-thread), chunk-XOR pre-applied to source ----
  const int hs = (tid & 7) ^ ((tid >> 3) & 7);
  const f16* gA = A + (size_t)(row0 + (tid >> 3)) * DIM + (hs >> 2) * 32 +
                  (hs & 3) * 8;
  const f16* gB = Bt + (size_t)(col0 + (tid >> 3)) * DIM + (hs >> 2) * 32 +
                  (hs & 3) * 8;
  f16* AsW = As + wid * 512;            // wave-uniform LDS dest bases
  f16* BsW = Bs + wid * 512;

  // ---- fragment read bases (per half), XOR folded per-thread ----
  const int g = lane >> 4;
  const int r7 = la15 & 7;
  const int cs0 = (g ^ r7) * 8;             // half 0 chunk
  const int cs1 = ((4 + g) ^ r7) * 8;       // half 1 chunk
  const f16* aB0 = As + (wm + la15) * 64 + cs0;
  const f16* aB1 = As + (wm + la15) * 64 + cs1;
  const f16* bB0 = Bs + (wn + la15) * 64 + cs0;
  const f16* bB1 = Bs + (wn + la15) * 64 + cs1;

  f32x4 acc[10][4];
#pragma unroll
  for (int i = 0; i < 10; i++)
#pragma unroll
    for (int j = 0; j < 4; j++) acc[i][j] = (f32x4){0.f, 0.f, 0.f, 0.f};
  f16x8 af[5], bf[4];

  // prologue: tile 0 into buf0, drain fully
  STAGE_AB(0, 0);
  __builtin_amdgcn_sched_barrier(0);
  WT0;
  __builtin_amdgcn_s_barrier();
  __builtin_amdgcn_sched_barrier(0);

#pragma unroll 1
  for (int it = 0; it < 7; ++it) {
    const int t1 = 2 * it + 1, t2 = 2 * it + 2;
    TILE(0, STAGE_A(1, t1), STAGE_B(1, t1), WT0)
    TILE(1, STAGE_A(0, t2), STAGE_B(0, t2), WT0)
  }
  TILE(0, STAGE_A(1, 15), STAGE_B(1, 15), WT0)
  TILE(1, STN, STN, WTN)

  // ---- per-head normalization (per-element row predicate: BM=320 blocks
  //      can straddle the k/v boundary at row 12288) ----
  const int crow = (lane >> 4) * 4;
#pragma unroll
  for (int mh = 0; mh < 2; ++mh)
#pragma unroll
    for (int f = 0; f < 5; ++f) {
      const int m = mh * 5 + f;
      const int rbase = row0 + wm + mh * 80 + f * 16 + crow;
#pragma unroll
      for (int r = 0; r < 4; ++r) {
        float s = acc[m][0][r] * acc[m][0][r] + acc[m][1][r] * acc[m][1][r]
                + acc[m][2][r] * acc[m][2][r] + acc[m][3][r] * acc[m][3][r];
        s += __shfl_xor(s, 1);
        s += __shfl_xor(s, 2);
        s += __shfl_xor(s, 4);
        s += __shfl_xor(s, 8);
        if (rbase + r < RQ + RK) {
          const float inv = rsqrtf(s);
#pragma unroll
          for (int j = 0; j < 4; ++j) acc[m][j][r] *= inv;
        }
      }
    }

  // ---- epilogue: LDS-transpose to full-line 16B-contiguous stores ----
  // scratch overlays As: [2 halves][16 rows][264 cols] f16 (16.9 KB)
  f16* sc = As;
  const int wmi = wid >> 2;
  const int ehalf = tid >> 8;
  const int err = (tid >> 4) & 15;
  const int ecc = tid & 15;
  const f16* rb_l = sc + ehalf * (16 * 264) + err * 264 + ecc * 16;
#pragma unroll
  for (int mh = 0; mh < 2; ++mh)
#pragma unroll
    for (int f = 0; f < 5; ++f) {
      const int m = mh * 5 + f;
#pragma unroll
      for (int j = 0; j < 4; ++j)
#pragma unroll
        for (int r = 0; r < 4; ++r)
          sc[wmi * (16 * 264) + (crow + r) * 264 + wn + j * 16 + la15] =
              (f16)acc[m][j][r];
      __syncthreads();
      f16x8 v0 = *(const f16x8*)(rb_l);
      f16x8 v1 = *(const f16x8*)(rb_l + 8);
      const int grow = row0 + ehalf * 160 + mh * 80 + f * 16 + err;
      f16* Cp = C + (size_t)grow * DIM + col0 + ecc * 16;
      *(f16x8*)(Cp) = v0;
      *(f16x8*)(Cp + 8) = v1;
      if (!(mh == 1 && f == 4)) __syncthreads();
    }
}

// ---------------------------------------------------------------------------
// MFMA fp16 GEMM (kept for the final GEMM, MT=64 path).
// ---------------------------------------------------------------------------
template <int MT, bool OUT_F16, bool NORMS, bool BIAS, bool PERB>
__global__ void __launch_bounds__(256) mfma_gemm(
    const f16* __restrict__ A, const f16* __restrict__ Bt,
    void* __restrict__ Cout, const float* __restrict__ bias) {
  constexpr int JT = (MT == 128) ? 4 : 2;
  __shared__ f16 Asl[2][MT * 32];
  __shared__ f16 Bsl[2][128 * 32];
  const int t = threadIdx.x;
  const int wid = t >> 6;
  const int lane = t & 63;
  const int row0 = blockIdx.x * MT;
  const int col0 = blockIdx.y * 128;
  const int wm = (MT == 128) ? (wid >> 1) * 64 : 0;
  const int wn = (MT == 128) ? (wid & 1) * 64 : wid * 32;

  const f16* BtB = PERB ? Bt + (size_t)(row0 >> 10) * DIM * DIM : Bt;

  const int rB = 32 * wid + (lane >> 2);
  const int qB = ((lane & 3) - ((rB >> 1) & 3)) & 3;
  const f16* gB = BtB + (size_t)(col0 + rB) * DIM + qB * 8;
  f16* lB0 = Bsl[0] + 32 * wid * 32;
  f16* lB1 = Bsl[1] + 32 * wid * 32;
  const int rA = (MT == 128 ? 32 : 16) * wid + (lane >> 2);
  const int qA = ((lane & 3) - ((rA >> 1) & 3)) & 3;
  const f16* gA = A + (size_t)(row0 + rA) * DIM + qA * 8;
  f16* lA0 = Asl[0] + (MT == 128 ? 32 : 16) * wid * 32;
  f16* lA1 = Asl[1] + (MT == 128 ? 32 : 16) * wid * 32;

  f32x4 acc[4][JT];
#pragma unroll
  for (int i = 0; i < 4; i++)
#pragma unroll
    for (int j = 0; j < JT; j++) acc[i][j] = (f32x4){0.f, 0.f, 0.f, 0.f};

  const int mrow = lane & 15;
  const int kq_p = (((lane >> 4) + ((lane >> 1) & 3)) & 3) * 8;

  for (int kt = 0; kt < DIM / 64; ++kt) {
    if (kt) __syncthreads();
    const int ko = kt * 64;
    async16(gA + ko,      lA0);
    if (MT == 128) async16(gA + ko + 16 * DIM, lA0 + 512);
    async16(gB + ko,      lB0);
    async16(gB + ko + 16 * DIM, lB0 + 512);
    async16(gA + ko + 32, lA1);
    if (MT == 128) async16(gA + ko + 32 + 16 * DIM, lA1 + 512);
    async16(gB + ko + 32, lB1);
    async16(gB + ko + 32 + 16 * DIM, lB1 + 512);
    __syncthreads();

#pragma unroll
    for (int h = 0; h < 2; ++h) {
      f16x8 af[4], bf[JT];
#pragma unroll
      for (int i = 0; i < 4; i++)
        af[i] = *(const f16x8*)(Asl[h] + (wm + i * 16 + mrow) * 32 + kq_p);
#pragma unroll
      for (int j = 0; j < JT; j++)
        bf[j] = *(const f16x8*)(Bsl[h] + (wn + j * 16 + mrow) * 32 + kq_p);
#pragma unroll
      for (int i = 0; i < 4; i++)
#pragma unroll
        for (int j = 0; j < JT; j++)
          acc[i][j] = __builtin_amdgcn_mfma_f32_16x16x32_f16(af[i], bf[j], acc[i][j], 0, 0, 0);
    }
  }

  if (NORMS && MT == 128) {
    if (row0 < RQ + RK) {
      float sums[4][4];
#pragma unroll
      for (int i = 0; i < 4; i++)
#pragma unroll
        for (int r = 0; r < 4; r++) {
          float s = 0.f;
#pragma unroll
          for (int j = 0; j < JT; j++) s += acc[i][j][r] * acc[i][j][r];
          sums[i][r] = s;
        }
#pragma unroll
      for (int off = 1; off < 16; off <<= 1)
#pragma unroll
        for (int i = 0; i < 4; i++)
#pragma unroll
          for (int r = 0; r < 4; r++)
            sums[i][r] += __shfl_xor(sums[i][r], off);
#pragma unroll
      for (int i = 0; i < 4; i++)
#pragma unroll
        for (int r = 0; r < 4; r++) {
          const float inv = rsqrtf(sums[i][r]);
#pragma unroll
          for (int j = 0; j < JT; j++) acc[i][j][r] *= inv;
        }
    }
  }

  const int ccol = lane & 15;
  const int crow = (lane >> 4) * 4;
  if (OUT_F16) {
    f16* C = (f16*)Cout;
#pragma unroll
    for (int j = 0; j < JT; j++) {
      const int col = col0 + wn + j * 16 + ccol;
#pragma unroll
      for (int i = 0; i < 4; i++) {
        f16* Cp = C + (size_t)(row0 + wm + i * 16 + crow) * DIM + col;
#pragma unroll
        for (int r = 0; r < 4; r++) Cp[(size_t)r * DIM] = (f16)acc[i][j][r];
      }
    }
  } else {
    float* C = (float*)Cout;
#pragma unroll
    for (int j = 0; j < JT; j++) {
      const int col = col0 + wn + j * 16 + ccol;
      float bv = BIAS ? bias[col] : 0.f;
#pragma unroll
      for (int i = 0; i < 4; i++) {
        float* Cp = C + (size_t)(row0 + wm + i * 16 + crow) * DIM + col;
#pragma unroll
        for (int r = 0; r < 4; r++) Cp[(size_t)r * DIM] = acc[i][j][r] + bv;
      }
    }
  }
}

// ---------------------------------------------------------------------------
// K3: per-(slice,b,h) partial S = sum over 256 m of g_k[m] outer f_v[m].
// ---------------------------------------------------------------------------
__global__ void __launch_bounds__(256) s_kernel(
    const f16* __restrict__ f, float* __restrict__ S4) {
  const int bh = blockIdx.x;
  const int b = bh >> 4, h = bh & 15;
  const int mbase = blockIdx.y * (SEQK / NSLC);
  const int t = threadIdx.x;
  __shared__ float ks[32][68];
  __shared__ float vs[32][68];
  const int lm   = t >> 3;
  const int lseg = (t & 7) * 8;
  const int d1 = (t & 15) * 4;
  const int d2 = (t >> 4) * 4;
  float acc[4][4] = {{0.f}};
  const f16* fk_base = f + ((size_t)RQ + (size_t)b * SEQK) * DIM + h * DH;
  const f16* fv_base = f + ((size_t)RQ + RK + (size_t)b * SEQK) * DIM + h * DH;

  int m = mbase + lm;
  f16x8 kv = *(const f16x8*)(fk_base + (size_t)m * DIM + lseg);
  f16x8 vv = *(const f16x8*)(fv_base + (size_t)m * DIM + lseg);

  constexpr int SUBS = SEQK / NSLC / 32;  // 8
  for (int sub = 0; sub < SUBS; ++sub) {
    __syncthreads();
#pragma unroll
    for (int e = 0; e < 8; e++) {
      ks[lm][lseg + e] = (float)kv[e];
      vs[lm][lseg + e] = (float)vv[e];
    }
    __syncthreads();
    if (sub + 1 < SUBS) {
      m = mbase + (sub + 1) * 32 + lm;
      kv = *(const f16x8*)(fk_base + (size_t)m * DIM + lseg);
      vv = *(const f16x8*)(fv_base + (size_t)m * DIM + lseg);
    }
#pragma unroll
    for (int mm = 0; mm < 32; ++mm) {
      float4 kk = *(const float4*)&ks[mm][d1];
      float4 vv2 = *(const float4*)&vs[mm][d2];
      acc[0][0] = fmaf(kk.x, vv2.x, acc[0][0]);
      acc[0][1] = fmaf(kk.x, vv2.y, acc[0][1]);
      acc[0][2] = fmaf(kk.x, vv2.z, acc[0][2]);
      acc[0][3] = fmaf(kk.x, vv2.w, acc[0][3]);
      acc[1][0] = fmaf(kk.y, vv2.x, acc[1][0]);
      acc[1][1] = fmaf(kk.y, vv2.y, acc[1][1]);
      acc[1][2] = fmaf(kk.y, vv2.z, acc[1][2]);
      acc[1][3] = fmaf(kk.y, vv2.w, acc[1][3]);
      acc[2][0] = fmaf(kk.z, vv2.x, acc[2][0]);
      acc[2][1] = fmaf(kk.z, vv2.y, acc[2][1]);
      acc[2][2] = fmaf(kk.z, vv2.z, acc[2][2]);
      acc[2][3] = fmaf(kk.z, vv2.w, acc[2][3]);
      acc[3][0] = fmaf(kk.w, vv2.x, acc[3][0]);
      acc[3][1] = fmaf(kk.w, vv2.y, acc[3][1]);
      acc[3][2] = fmaf(kk.w, vv2.z, acc[3][2]);
      acc[3][3] = fmaf(kk.w, vv2.w, acc[3][3]);
    }
  }
  float* Sp = S4 + ((size_t)blockIdx.y * BH + bh) * DH * DH;
#pragma unroll
  for (int i = 0; i < 4; i++)
#pragma unroll
    for (int j = 0; j < 4; j++)
      Sp[(d1 + i) * DH + (d2 + j)] = acc[i][j];
}

// ---------------------------------------------------------------------------
// K3b: sum the NSLC partial S slices -> Sh fp16 [bh][d1][d2] row-major.
// ---------------------------------------------------------------------------
__global__ void __launch_bounds__(256) s_reduce(
    const float* __restrict__ S4, f16* __restrict__ Sh) {
  const int bh = blockIdx.x;
  const int t = threadIdx.x;
  const size_t base = (size_t)bh * DH * DH + t * 16;
  constexpr size_t STR = (size_t)BH * DH * DH;
#pragma unroll
  for (int c = 0; c < 4; c++) {
    float4 s = {0.f, 0.f, 0.f, 0.f};
#pragma unroll
    for (int p = 0; p < NSLC; p++) {
      float4 sp = *(const float4*)(S4 + base + p * STR + 4 * c);
      s.x += sp.x; s.y += sp.y; s.z += sp.z; s.w += sp.w;
    }
    union { f16 h[4]; uint2 u; } o;
    o.h[0] = (f16)s.x; o.h[1] = (f16)s.y; o.h[2] = (f16)s.z; o.h[3] = (f16)s.w;
    *(uint2*)(Sh + base + 4 * c) = o.u;
  }
}

// ---------------------------------------------------------------------------
// K3c: Mt[b][n][64h+d1] = sum_d2 wt_out[n][64h+d2] * Sh[b,h][d1][d2]
// ---------------------------------------------------------------------------
__global__ void __launch_bounds__(256) m_build(
    const f16* __restrict__ wt_out, const f16* __restrict__ Sh,
    f16* __restrict__ Mt) {
  const int n0 = blockIdx.x * 128;
  const int bh = blockIdx.y;
  const int b = bh >> 4, h = bh & 15;
  __shared__ f16 Asl[128 * 64];
  __shared__ f16 Bsl[64 * 64];
  const int t = threadIdx.x;
  const int wid = t >> 6, lane = t & 63;

  const f16* gA = wt_out + (size_t)(n0 + 32 * wid + (lane >> 3)) * DIM
                  + 64 * h + (lane & 7) * 8;
  f16* lA = Asl + 32 * wid * 64;
  const f16* gB = Sh + (size_t)bh * DH * DH + (16 * wid + (lane >> 3)) * 64
                  + (lane & 7) * 8;
  f16* lB = Bsl + 16 * wid * 64;
#pragma unroll
  for (int o = 0; o < 4; o++) async16(gA + (size_t)(8 * o) * DIM, lA + 8 * o * 64);
  async16(gB, lB);
  async16(gB + 8 * 64, lB + 8 * 64);
  __syncthreads();

  const int wm = (wid >> 1) * 64;
  const int wn = (wid & 1) * 32;
  const int mrow = lane & 15;
  f32x4 acc[4][2];
#pragma unroll
  for (int i = 0; i < 4; i++)
#pragma unroll
    for (int j = 0; j < 2; j++) acc[i][j] = (f32x4){0.f, 0.f, 0.f, 0.f};

#pragma unroll
  for (int kh = 0; kh < 2; kh++) {
    const int kq = kh * 32 + (lane >> 4) * 8;
    f16x8 af[4], bf[2];
#pragma unroll
    for (int i = 0; i < 4; i++)
      af[i] = *(const f16x8*)(Asl + (wm + i * 16 + mrow) * 64 + kq);
#pragma unroll
    for (int j = 0; j < 2; j++)
      bf[j] = *(const f16x8*)(Bsl + (wn + j * 16 + mrow) * 64 + kq);
#pragma unroll
    for (int i = 0; i < 4; i++)
#pragma unroll
      for (int j = 0; j < 2; j++)
        acc[i][j] = __builtin_amdgcn_mfma_f32_16x16x32_f16(af[i], bf[j], acc[i][j], 0, 0, 0);
  }

  const int ccol = lane & 15;
  const int crow = (lane >> 4) * 4;
  f16* Mb = Mt + (size_t)b * DIM * DIM;
#pragma unroll
  for (int j = 0; j < 2; j++) {
    const int col = 64 * h + wn + j * 16 + ccol;
#pragma unroll
    for (int i = 0; i < 4; i++) {
      f16* Mp = Mb + (size_t)(n0 + wm + i * 16 + crow) * DIM + col;
#pragma unroll
      for (int r = 0; r < 4; r++) Mp[(size_t)r * DIM] = (f16)acc[i][j][r];
    }
  }
}

// ---------------------------------------------------------------------------
extern "C" void kernel_launch(void* const* d_in, const int* in_sizes, int n_in,
                              void* d_out, int out_size, void* d_ws, size_t ws_size,
                              hipStream_t stream) {
  const float* q     = (const float*)d_in[0];
  const float* k     = (const float*)d_in[1];
  const float* v     = (const float*)d_in[2];
  const float* gamma = (const float*)d_in[3];
  const float* beta  = (const float*)d_in[4];
  const float* W_in  = (const float*)d_in[5];
  const float* W_out = (const float*)d_in[6];
  const float* b_out = (const float*)d_in[7];
  float* out = (float*)d_out;

  // workspace layout
  char* w = (char*)d_ws;
  f16*   f      = (f16*)w;                                     // 40 MB
  f16*   a_h    = f + (size_t)RTOT * DIM;                      // 40 MB
  f16*   wt_in  = a_h + (size_t)RTOT * DIM;                    // 2 MB
  f16*   wt_out = wt_in + (size_t)DIM * DIM;                   // 2 MB
  f16*   Mt     = wt_out + (size_t)DIM * DIM;                  // 8 MB
  f16*   Sh     = Mt + (size_t)BATCH * DIM * DIM;              // 512 KB
  float* S4     = (float*)(Sh + (size_t)BH * DH * DH);         // 8 MB

  ln_to_f16<<<RTOT / 4, 256, 0, stream>>>(q, k, v, gamma, beta, a_h);
  transpose_f16<<<dim3(DIM / 32, DIM / 32, 2), 256, 0, stream>>>(
      W_in, W_out, wt_in, wt_out);

  // f = LN(t) @ W_in for all rows; q/k rows pre-normalized per head
  proj_gemm<<<dim3(256), 512, 0, stream>>>(a_h, wt_in, f);

  s_kernel<<<dim3(BH, NSLC), 256, 0, stream>>>(f, S4);

  s_reduce<<<BH, 256, 0, stream>>>(S4, Sh);

  m_build<<<dim3(DIM / 128, BH), 256, 0, stream>>>(wt_out, Sh, Mt);

  // out = g_q @ Mt[b]^T + b_out (per-batch weights)
  mfma_gemm<64, false, false, true, true>
      <<<dim3(RQ / 64, DIM / 128), 256, 0, stream>>>(f, Mt, out, b_out);
}

// Round 7
// 229.005 us; speedup vs baseline: 1.0906x; 1.0046x over previous
//
#include <hip/hip_runtime.h>

// Problem constants
constexpr int BATCH = 4;
constexpr int SEQQ  = 1024;
constexpr int SEQK  = 2048;
constexpr int DIM   = 1024;
constexpr int NH    = 16;
constexpr int DH    = 64;
constexpr int RQ    = BATCH * SEQQ;          // 4096 q rows
constexpr int RK    = BATCH * SEQK;          // 8192 k rows (== v rows)
constexpr int RTOT  = RQ + 2 * RK;           // 20480
constexpr int BH    = BATCH * NH;            // 64
constexpr int NSLC  = 8;                     // s_kernel K-slices
constexpr float LN_EPS = 1e-5f;

typedef _Float16 f16;
typedef __attribute__((ext_vector_type(8))) _Float16 f16x8;
typedef __attribute__((ext_vector_type(4))) float f32x4;

__device__ __forceinline__ void async16(const void* g, void* l) {
  __builtin_amdgcn_global_load_lds(
      (const __attribute__((address_space(1))) void*)g,
      (__attribute__((address_space(3))) void*)l, 16, 0, 0);
}

// ---------------------------------------------------------------------------
// K0: fused {LayerNorm -> fp16} + {W transpose -> fp16} in one launch.
//   blocks [0, RTOT/4): LN, one wave per row.
//   blocks [RTOT/4, RTOT/4 + 2048): 32x32 transpose tiles of W_in / W_out.
// ---------------------------------------------------------------------------
__global__ void __launch_bounds__(256) pre_kernel(
    const float* __restrict__ q, const float* __restrict__ k,
    const float* __restrict__ v, const float* __restrict__ gamma,
    const float* __restrict__ beta, f16* __restrict__ a_h,
    const float* __restrict__ W0, const float* __restrict__ W1,
    f16* __restrict__ T0, f16* __restrict__ T1) {
  __shared__ float tile[32][33];
  if (blockIdx.x < RTOT / 4) {
    const int row = blockIdx.x * 4 + (threadIdx.x >> 6);
    const int lane = threadIdx.x & 63;
    const float* src;
    if (row < RQ)            src = q + (size_t)row * DIM;
    else if (row < RQ + RK)  src = k + (size_t)(row - RQ) * DIM;
    else                     src = v + (size_t)(row - RQ - RK) * DIM;
    float4 x[4];
    float s = 0.f, s2 = 0.f;
#pragma unroll
    for (int c = 0; c < 4; c++) {
      x[c] = ((const float4*)src)[c * 64 + lane];
      s  += x[c].x + x[c].y + x[c].z + x[c].w;
      s2 += x[c].x * x[c].x + x[c].y * x[c].y + x[c].z * x[c].z + x[c].w * x[c].w;
    }
#pragma unroll
    for (int off = 1; off < 64; off <<= 1) {
      s  += __shfl_xor(s, off);
      s2 += __shfl_xor(s2, off);
    }
    const float mu = s / DIM;
    const float rs = rsqrtf(s2 / DIM - mu * mu + LN_EPS);
#pragma unroll
    for (int c = 0; c < 4; c++) {
      float4 g = ((const float4*)gamma)[c * 64 + lane];
      float4 b = ((const float4*)beta)[c * 64 + lane];
      union { f16 h[4]; uint2 u; } o;
      o.h[0] = (f16)((x[c].x - mu) * rs * g.x + b.x);
      o.h[1] = (f16)((x[c].y - mu) * rs * g.y + b.y);
      o.h[2] = (f16)((x[c].z - mu) * rs * g.z + b.z);
      o.h[3] = (f16)((x[c].w - mu) * rs * g.w + b.w);
      ((uint2*)(a_h + (size_t)row * DIM))[c * 64 + lane] = o.u;
    }
  } else {
    const int tz = blockIdx.x - RTOT / 4;
    const float* W = (tz >= 1024) ? W1 : W0;
    f16* T = (tz >= 1024) ? T1 : T0;
    const int rem = tz & 1023;
    const int k0 = (rem & 31) * 32, n0 = (rem >> 5) * 32;
    int tx = threadIdx.x & 31, ty = threadIdx.x >> 5;
#pragma unroll
    for (int i = 0; i < 4; i++)
      tile[ty + 8 * i][tx] = W[(size_t)(k0 + ty + 8 * i) * DIM + n0 + tx];
    __syncthreads();
#pragma unroll
    for (int i = 0; i < 4; i++)
      T[(size_t)(n0 + ty + 8 * i) * DIM + k0 + tx] = (f16)tile[tx][ty + 8 * i];
  }
}

// ---------------------------------------------------------------------------
// K1: projection GEMM, 320x256 tile -> grid 256 blocks = 1 per CU.
//     ONE barrier per K-tile (16 barriers total in the main loop).
//
// Per tile t (buf p = t&1):
//   s_barrier                     [publishes tile t's data + frees buf p^1]
//   STAGE_AB(t+1 -> p^1)          [9 async16]
//   reads(p) + 80 MFMA            [compiler-counted lgkmcnt]
//   vmcnt(0)                      [drains own t+1 DMAs before next barrier]
// Race-freedom: a wave's reads of buf x drain (lgkmcnt before its MFMA)
// before it reaches the next barrier; the stage into p^1 is issued only
// after the barrier that proves all waves' p^1 reads retired; each wave's
// vmcnt(0) before the barrier publishes its own DMA writes.
//
// Epilogue: per-head norm, then acc -> LDS scratch -> 16B-contiguous
// stores (full 64B lines; WRITE_SIZE stays at the ideal 40 MB).
// ---------------------------------------------------------------------------
constexpr int PT_A = 320 * 64;   // f16 per A tile buffer (20480)
constexpr int PT_B = 256 * 64;   // f16 per B tile buffer (16384)

#define STAGE_A(buf, kt) do {                                        \
    const f16* s_ = gA + (size_t)(kt) * 64;                          \
    f16* d_ = AsW + (buf) * PT_A;                                    \
    async16(s_,          d_);                                        \
    async16(s_ +  65536, d_ + 4096);                                 \
    async16(s_ + 131072, d_ + 8192);                                 \
    async16(s_ + 196608, d_ + 12288);                                \
    async16(s_ + 262144, d_ + 16384);                                \
  } while (0)

#define STAGE_B(buf, kt) do {                                        \
    const f16* s_ = gB + (size_t)(kt) * 64;                          \
    f16* d_ = BsW + (buf) * PT_B;                                    \
    async16(s_,          d_);                                        \
    async16(s_ +  65536, d_ + 4096);                                 \
    async16(s_ + 131072, d_ + 8192);                                 \
    async16(s_ + 196608, d_ + 12288);                                \
  } while (0)

#define STAGE_AB(buf, kt) do { STAGE_A(buf, kt); STAGE_B(buf, kt); } while (0)

#define WT0 asm volatile("s_waitcnt vmcnt(0)" ::: "memory")
#define WTN ((void)0)
#define STN ((void)0)

#define HALF(BUF, H)                                                 \
    _Pragma("unroll") for (int j_ = 0; j_ < 4; ++j_)                 \
      bf[j_] = *(const f16x8*)(bB##H + (BUF) * PT_B + j_ * 1024);    \
    _Pragma("unroll") for (int f_ = 0; f_ < 5; ++f_)                 \
      af0[f_] = *(const f16x8*)(aB##H + (BUF) * PT_A + f_ * 1024);   \
    _Pragma("unroll") for (int f_ = 0; f_ < 5; ++f_)                 \
      af1[f_] = *(const f16x8*)(aB##H + (BUF) * PT_A + 5120 +        \
                                f_ * 1024);                          \
    __builtin_amdgcn_s_setprio(1);                                   \
    _Pragma("unroll") for (int f_ = 0; f_ < 5; ++f_)                 \
      _Pragma("unroll") for (int j_ = 0; j_ < 4; ++j_)               \
        acc[f_][j_] = __builtin_amdgcn_mfma_f32_16x16x32_f16(        \
            af0[f_], bf[j_], acc[f_][j_], 0, 0, 0);                  \
    _Pragma("unroll") for (int f_ = 0; f_ < 5; ++f_)                 \
      _Pragma("unroll") for (int j_ = 0; j_ < 4; ++j_)               \
        acc[5 + f_][j_] = __builtin_amdgcn_mfma_f32_16x16x32_f16(    \
            af1[f_], bf[j_], acc[5 + f_][j_], 0, 0, 0);              \
    __builtin_amdgcn_s_setprio(0);

#define PTILE(BUF, STG, TVW) {                                       \
    __builtin_amdgcn_s_barrier();                                    \
    __builtin_amdgcn_sched_barrier(0);                               \
    STG;                                                             \
    HALF(BUF, 0)                                                     \
    HALF(BUF, 1)                                                     \
    __builtin_amdgcn_sched_barrier(0);                               \
    TVW;                                                             \
  }

__global__ void __launch_bounds__(512, 2) proj_gemm(
    const f16* __restrict__ A, const f16* __restrict__ Bt,
    f16* __restrict__ C) {
  __shared__ __align__(16) f16 As[2 * PT_A];   // 80 KB
  __shared__ __align__(16) f16 Bs[2 * PT_B];   // 64 KB

  const int tid = threadIdx.x;
  const int wid = tid >> 6;
  const int lane = tid & 63;
  const int la15 = lane & 15;

  // bijective XCD swizzle (256 % 8 == 0); col-tile fastest within an XCD
  // chunk so a row-panel's 4 column tiles share one XCD's L2.
  const int bid = blockIdx.x;
  const int swz = (bid & 7) * 32 + (bid >> 3);
  const int row0 = (swz >> 2) * 320;
  const int col0 = (swz & 3) * 256;

  const int wm = (wid >> 2) * 160;      // warp_m in {0,1}
  const int wn = (wid & 3) * 64;        // warp_n in {0..3}

  // ---- staging source (per-thread), chunk-XOR pre-applied to source ----
  const int hs = (tid & 7) ^ ((tid >> 3) & 7);
  const f16* gA = A + (size_t)(row0 + (tid >> 3)) * DIM + (hs >> 2) * 32 +
                  (hs & 3) * 8;
  const f16* gB = Bt + (size_t)(col0 + (tid >> 3)) * DIM + (hs >> 2) * 32 +
                  (hs & 3) * 8;
  f16* AsW = As + wid * 512;            // wave-uniform LDS dest bases
  f16* BsW = Bs + wid * 512;

  // ---- fragment read bases (per half), XOR folded per-thread ----
  const int g = lane >> 4;
  const int r7 = la15 & 7;
  const int cs0 = (g ^ r7) * 8;             // half 0 chunk
  const int cs1 = ((4 + g) ^ r7) * 8;       // half 1 chunk
  const f16* aB0 = As + (wm + la15) * 64 + cs0;
  const f16* aB1 = As + (wm + la15) * 64 + cs1;
  const f16* bB0 = Bs + (wn + la15) * 64 + cs0;
  const f16* bB1 = Bs + (wn + la15) * 64 + cs1;

  f32x4 acc[10][4];
#pragma unroll
  for (int i = 0; i < 10; i++)
#pragma unroll
    for (int j = 0; j < 4; j++) acc[i][j] = (f32x4){0.f, 0.f, 0.f, 0.f};
  f16x8 af0[5], af1[5], bf[4];

  // prologue: tile 0 into buf0, drain own DMAs (barrier at first PTILE)
  STAGE_AB(0, 0);
  __builtin_amdgcn_sched_barrier(0);
  WT0;

#pragma unroll 1
  for (int it = 0; it < 7; ++it) {
    const int t1 = 2 * it + 1, t2 = 2 * it + 2;
    PTILE(0, STAGE_AB(1, t1), WT0)
    PTILE(1, STAGE_AB(0, t2), WT0)
  }
  PTILE(0, STAGE_AB(1, 15), WT0)
  PTILE(1, STN, WTN)

  // ---- per-head normalization (per-element row predicate: BM=320 blocks
  //      can straddle the k/v boundary at row 12288) ----
  const int crow = (lane >> 4) * 4;
#pragma unroll
  for (int mh = 0; mh < 2; ++mh)
#pragma unroll
    for (int f = 0; f < 5; ++f) {
      const int m = mh * 5 + f;
      const int rbase = row0 + wm + mh * 80 + f * 16 + crow;
#pragma unroll
      for (int r = 0; r < 4; ++r) {
        float s = acc[m][0][r] * acc[m][0][r] + acc[m][1][r] * acc[m][1][r]
                + acc[m][2][r] * acc[m][2][r] + acc[m][3][r] * acc[m][3][r];
        s += __shfl_xor(s, 1);
        s += __shfl_xor(s, 2);
        s += __shfl_xor(s, 4);
        s += __shfl_xor(s, 8);
        if (rbase + r < RQ + RK) {
          const float inv = rsqrtf(s);
#pragma unroll
          for (int j = 0; j < 4; ++j) acc[m][j][r] *= inv;
        }
      }
    }

  // ---- epilogue: LDS-transpose to full-line 16B-contiguous stores ----
  // scratch overlays As buf0 (freed: last reads of buf0 were tile 14,
  // drained before the tile-15 barrier): [2][16][264] f16 (16.9 KB)
  f16* sc = As;
  const int wmi = wid >> 2;
  const int ehalf = tid >> 8;
  const int err = (tid >> 4) & 15;
  const int ecc = tid & 15;
  const f16* rb_l = sc + ehalf * (16 * 264) + err * 264 + ecc * 16;
#pragma unroll
  for (int mh = 0; mh < 2; ++mh)
#pragma unroll
    for (int f = 0; f < 5; ++f) {
      const int m = mh * 5 + f;
#pragma unroll
      for (int j = 0; j < 4; ++j)
#pragma unroll
        for (int r = 0; r < 4; ++r)
          sc[wmi * (16 * 264) + (crow + r) * 264 + wn + j * 16 + la15] =
              (f16)acc[m][j][r];
      __syncthreads();
      f16x8 v0 = *(const f16x8*)(rb_l);
      f16x8 v1 = *(const f16x8*)(rb_l + 8);
      const int grow = row0 + ehalf * 160 + mh * 80 + f * 16 + err;
      f16* Cp = C + (size_t)grow * DIM + col0 + ecc * 16;
      *(f16x8*)(Cp) = v0;
      *(f16x8*)(Cp + 8) = v1;
      if (!(mh == 1 && f == 4)) __syncthreads();
    }
}

// ---------------------------------------------------------------------------
// K3: per-(slice,b,h) partial S = sum over 256 m of g_k[m] outer f_v[m].
// ---------------------------------------------------------------------------
__global__ void __launch_bounds__(256) s_kernel(
    const f16* __restrict__ f, float* __restrict__ S4) {
  const int bh = blockIdx.x;
  const int b = bh >> 4, h = bh & 15;
  const int mbase = blockIdx.y * (SEQK / NSLC);
  const int t = threadIdx.x;
  __shared__ float ks[32][68];
  __shared__ float vs[32][68];
  const int lm   = t >> 3;
  const int lseg = (t & 7) * 8;
  const int d1 = (t & 15) * 4;
  const int d2 = (t >> 4) * 4;
  float acc[4][4] = {{0.f}};
  const f16* fk_base = f + ((size_t)RQ + (size_t)b * SEQK) * DIM + h * DH;
  const f16* fv_base = f + ((size_t)RQ + RK + (size_t)b * SEQK) * DIM + h * DH;

  int m = mbase + lm;
  f16x8 kv = *(const f16x8*)(fk_base + (size_t)m * DIM + lseg);
  f16x8 vv = *(const f16x8*)(fv_base + (size_t)m * DIM + lseg);

  constexpr int SUBS = SEQK / NSLC / 32;  // 8
  for (int sub = 0; sub < SUBS; ++sub) {
    __syncthreads();
#pragma unroll
    for (int e = 0; e < 8; e++) {
      ks[lm][lseg + e] = (float)kv[e];
      vs[lm][lseg + e] = (float)vv[e];
    }
    __syncthreads();
    if (sub + 1 < SUBS) {
      m = mbase + (sub + 1) * 32 + lm;
      kv = *(const f16x8*)(fk_base + (size_t)m * DIM + lseg);
      vv = *(const f16x8*)(fv_base + (size_t)m * DIM + lseg);
    }
#pragma unroll
    for (int mm = 0; mm < 32; ++mm) {
      float4 kk = *(const float4*)&ks[mm][d1];
      float4 vv2 = *(const float4*)&vs[mm][d2];
      acc[0][0] = fmaf(kk.x, vv2.x, acc[0][0]);
      acc[0][1] = fmaf(kk.x, vv2.y, acc[0][1]);
      acc[0][2] = fmaf(kk.x, vv2.z, acc[0][2]);
      acc[0][3] = fmaf(kk.x, vv2.w, acc[0][3]);
      acc[1][0] = fmaf(kk.y, vv2.x, acc[1][0]);
      acc[1][1] = fmaf(kk.y, vv2.y, acc[1][1]);
      acc[1][2] = fmaf(kk.y, vv2.z, acc[1][2]);
      acc[1][3] = fmaf(kk.y, vv2.w, acc[1][3]);
      acc[2][0] = fmaf(kk.z, vv2.x, acc[2][0]);
      acc[2][1] = fmaf(kk.z, vv2.y, acc[2][1]);
      acc[2][2] = fmaf(kk.z, vv2.z, acc[2][2]);
      acc[2][3] = fmaf(kk.z, vv2.w, acc[2][3]);
      acc[3][0] = fmaf(kk.w, vv2.x, acc[3][0]);
      acc[3][1] = fmaf(kk.w, vv2.y, acc[3][1]);
      acc[3][2] = fmaf(kk.w, vv2.z, acc[3][2]);
      acc[3][3] = fmaf(kk.w, vv2.w, acc[3][3]);
    }
  }
  float* Sp = S4 + ((size_t)blockIdx.y * BH + bh) * DH * DH;
#pragma unroll
  for (int i = 0; i < 4; i++)
#pragma unroll
    for (int j = 0; j < 4; j++)
      Sp[(d1 + i) * DH + (d2 + j)] = acc[i][j];
}

// ---------------------------------------------------------------------------
// K3b: sum the NSLC partial S slices -> Sh fp16 [bh][d1][d2] row-major.
// ---------------------------------------------------------------------------
__global__ void __launch_bounds__(256) s_reduce(
    const float* __restrict__ S4, f16* __restrict__ Sh) {
  const int bh = blockIdx.x;
  const int t = threadIdx.x;
  const size_t base = (size_t)bh * DH * DH + t * 16;
  constexpr size_t STR = (size_t)BH * DH * DH;
#pragma unroll
  for (int c = 0; c < 4; c++) {
    float4 s = {0.f, 0.f, 0.f, 0.f};
#pragma unroll
    for (int p = 0; p < NSLC; p++) {
      float4 sp = *(const float4*)(S4 + base + p * STR + 4 * c);
      s.x += sp.x; s.y += sp.y; s.z += sp.z; s.w += sp.w;
    }
    union { f16 h[4]; uint2 u; } o;
    o.h[0] = (f16)s.x; o.h[1] = (f16)s.y; o.h[2] = (f16)s.z; o.h[3] = (f16)s.w;
    *(uint2*)(Sh + base + 4 * c) = o.u;
  }
}

// ---------------------------------------------------------------------------
// K3c: Mt[b][n][64h+d1] = sum_d2 wt_out[n][64h+d2] * Sh[b,h][d1][d2]
// ---------------------------------------------------------------------------
__global__ void __launch_bounds__(256) m_build(
    const f16* __restrict__ wt_out, const f16* __restrict__ Sh,
    f16* __restrict__ Mt) {
  const int n0 = blockIdx.x * 128;
  const int bh = blockIdx.y;
  const int b = bh >> 4, h = bh & 15;
  __shared__ f16 Asl[128 * 64];
  __shared__ f16 Bsl[64 * 64];
  const int t = threadIdx.x;
  const int wid = t >> 6, lane = t & 63;

  const f16* gA = wt_out + (size_t)(n0 + 32 * wid + (lane >> 3)) * DIM
                  + 64 * h + (lane & 7) * 8;
  f16* lA = Asl + 32 * wid * 64;
  const f16* gB = Sh + (size_t)bh * DH * DH + (16 * wid + (lane >> 3)) * 64
                  + (lane & 7) * 8;
  f16* lB = Bsl + 16 * wid * 64;
#pragma unroll
  for (int o = 0; o < 4; o++) async16(gA + (size_t)(8 * o) * DIM, lA + 8 * o * 64);
  async16(gB, lB);
  async16(gB + 8 * 64, lB + 8 * 64);
  __syncthreads();

  const int wm = (wid >> 1) * 64;
  const int wn = (wid & 1) * 32;
  const int mrow = lane & 15;
  f32x4 acc[4][2];
#pragma unroll
  for (int i = 0; i < 4; i++)
#pragma unroll
    for (int j = 0; j < 2; j++) acc[i][j] = (f32x4){0.f, 0.f, 0.f, 0.f};

#pragma unroll
  for (int kh = 0; kh < 2; kh++) {
    const int kq = kh * 32 + (lane >> 4) * 8;
    f16x8 af[4], bf[2];
#pragma unroll
    for (int i = 0; i < 4; i++)
      af[i] = *(const f16x8*)(Asl + (wm + i * 16 + mrow) * 64 + kq);
#pragma unroll
    for (int j = 0; j < 2; j++)
      bf[j] = *(const f16x8*)(Bsl + (wn + j * 16 + mrow) * 64 + kq);
#pragma unroll
    for (int i = 0; i < 4; i++)
#pragma unroll
      for (int j = 0; j < 2; j++)
        acc[i][j] = __builtin_amdgcn_mfma_f32_16x16x32_f16(af[i], bf[j], acc[i][j], 0, 0, 0);
  }

  const int ccol = lane & 15;
  const int crow = (lane >> 4) * 4;
  f16* Mb = Mt + (size_t)b * DIM * DIM;
#pragma unroll
  for (int j = 0; j < 2; j++) {
    const int col = 64 * h + wn + j * 16 + ccol;
#pragma unroll
    for (int i = 0; i < 4; i++) {
      f16* Mp = Mb + (size_t)(n0 + wm + i * 16 + crow) * DIM + col;
#pragma unroll
      for (int r = 0; r < 4; r++) Mp[(size_t)r * DIM] = (f16)acc[i][j][r];
    }
  }
}

// ---------------------------------------------------------------------------
// K4: final GEMM out = g_q @ Mt[b]^T + b_out, 128x128 tile, 512 threads,
//     grid 256 = 1/CU (no tail). Same pipeline/swizzle as proj_gemm.
// ---------------------------------------------------------------------------
constexpr int FT_SZ = 128 * 64;   // f16 per tile buffer (8192)

#define FSTG(P, gp, kt, buf) do {                                    \
    const f16* s_ = (gp) + (size_t)(kt) * 64;                        \
    f16* d_ = (P) + (buf) * FT_SZ;                                   \
    async16(s_,         d_);                                         \
    async16(s_ + 65536, d_ + 4096);                                  \
  } while (0)

#define FHALF(BUF, H)                                                \
    _Pragma("unroll") for (int j_ = 0; j_ < 2; ++j_)                 \
      gbf[j_] = *(const f16x8*)(bB##H + (BUF) * FT_SZ + j_ * 1024);  \
    _Pragma("unroll") for (int i_ = 0; i_ < 4; ++i_)                 \
      gaf[i_] = *(const f16x8*)(aB##H + (BUF) * FT_SZ + i_ * 1024);  \
    __builtin_amdgcn_s_setprio(1);                                   \
    _Pragma("unroll") for (int i_ = 0; i_ < 4; ++i_)                 \
      _Pragma("unroll") for (int j_ = 0; j_ < 2; ++j_)               \
        facc[i_][j_] = __builtin_amdgcn_mfma_f32_16x16x32_f16(       \
            gaf[i_], gbf[j_], facc[i_][j_], 0, 0, 0);                \
    __builtin_amdgcn_s_setprio(0);

#define FTILE(BUF, STG, TVW) {                                       \
    __builtin_amdgcn_s_barrier();                                    \
    __builtin_amdgcn_sched_barrier(0);                               \
    STG;                                                             \
    FHALF(BUF, 0)                                                    \
    FHALF(BUF, 1)                                                    \
    __builtin_amdgcn_sched_barrier(0);                               \
    TVW;                                                             \
  }

__global__ void __launch_bounds__(512, 2) fin_gemm(
    const f16* __restrict__ f, const f16* __restrict__ Mt,
    const float* __restrict__ bias, float* __restrict__ out) {
  __shared__ __align__(16) f16 As[2 * FT_SZ];   // 32 KB
  __shared__ __align__(16) f16 Bs[2 * FT_SZ];   // 32 KB
  const int tid = threadIdx.x;
  const int wid = tid >> 6;
  const int lane = tid & 63;
  const int la15 = lane & 15;

  // XCD swizzle: 32 consecutive blocks per XCD share one batch's Mt in L2
  const int bid = blockIdx.x;
  const int swz = (bid & 7) * 32 + (bid >> 3);
  const int b  = swz >> 6;            // batch
  const int rt = (swz >> 3) & 7;      // row tile within batch
  const int ct = swz & 7;             // col tile
  const int grow0 = b * SEQQ + rt * 128;
  const int col0 = ct * 128;

  const int wm = (wid >> 2) * 64;     // warp_m in {0,1}
  const int wn = (wid & 3) * 32;      // warp_n in {0..3}

  const int hs = (tid & 7) ^ ((tid >> 3) & 7);
  const f16* gA = f + (size_t)(grow0 + (tid >> 3)) * DIM + (hs >> 2) * 32 +
                  (hs & 3) * 8;
  const f16* gB = Mt + (size_t)b * DIM * DIM +
                  (size_t)(col0 + (tid >> 3)) * DIM + (hs >> 2) * 32 +
                  (hs & 3) * 8;
  f16* AsW = As + wid * 512;
  f16* BsW = Bs + wid * 512;

  const int g = lane >> 4;
  const int r7 = la15 & 7;
  const int cs0 = (g ^ r7) * 8;
  const int cs1 = ((4 + g) ^ r7) * 8;
  const f16* aB0 = As + (wm + la15) * 64 + cs0;
  const f16* aB1 = As + (wm + la15) * 64 + cs1;
  const f16* bB0 = Bs + (wn + la15) * 64 + cs0;
  const f16* bB1 = Bs + (wn + la15) * 64 + cs1;

  f32x4 facc[4][2];
#pragma unroll
  for (int i = 0; i < 4; i++)
#pragma unroll
    for (int j = 0; j < 2; j++) facc[i][j] = (f32x4){0.f, 0.f, 0.f, 0.f};
  f16x8 gaf[4], gbf[2];

  FSTG(AsW, gA, 0, 0);
  FSTG(BsW, gB, 0, 0);
  __builtin_amdgcn_sched_barrier(0);
  WT0;

#pragma unroll 1
  for (int it = 0; it < 7; ++it) {
    const int t1 = 2 * it + 1, t2 = 2 * it + 2;
    FTILE(0, { FSTG(AsW, gA, t1, 1); FSTG(BsW, gB, t1, 1); }, WT0)
    FTILE(1, { FSTG(AsW, gA, t2, 0); FSTG(BsW, gB, t2, 0); }, WT0)
  }
  FTILE(0, { FSTG(AsW, gA, 15, 1); FSTG(BsW, gB, 15, 1); }, WT0)
  FTILE(1, STN, WTN)

  // epilogue: fp32 + bias; 16 lanes x 4B = full 64B line per row group
  const int crow = (lane >> 4) * 4;
#pragma unroll
  for (int j = 0; j < 2; ++j) {
    const int col = col0 + wn + j * 16 + la15;
    const float bv = bias[col];
#pragma unroll
    for (int i = 0; i < 4; ++i) {
      float* Op = out + (size_t)(grow0 + wm + i * 16 + crow) * DIM + col;
#pragma unroll
      for (int r = 0; r < 4; ++r) Op[(size_t)r * DIM] = facc[i][j][r] + bv;
    }
  }
}

// ---------------------------------------------------------------------------
extern "C" void kernel_launch(void* const* d_in, const int* in_sizes, int n_in,
                              void* d_out, int out_size, void* d_ws, size_t ws_size,
                              hipStream_t stream) {
  const float* q     = (const float*)d_in[0];
  const float* k     = (const float*)d_in[1];
  const float* v     = (const float*)d_in[2];
  const float* gamma = (const float*)d_in[3];
  const float* beta  = (const float*)d_in[4];
  const float* W_in  = (const float*)d_in[5];
  const float* W_out = (const float*)d_in[6];
  const float* b_out = (const float*)d_in[7];
  float* out = (float*)d_out;

  // workspace layout
  char* w = (char*)d_ws;
  f16*   f      = (f16*)w;                                     // 40 MB
  f16*   a_h    = f + (size_t)RTOT * DIM;                      // 40 MB
  f16*   wt_in  = a_h + (size_t)RTOT * DIM;                    // 2 MB
  f16*   wt_out = wt_in + (size_t)DIM * DIM;                   // 2 MB
  f16*   Mt     = wt_out + (size_t)DIM * DIM;                  // 8 MB
  f16*   Sh     = Mt + (size_t)BATCH * DIM * DIM;              // 512 KB
  float* S4     = (float*)(Sh + (size_t)BH * DH * DH);         // 8 MB

  pre_kernel<<<RTOT / 4 + 2048, 256, 0, stream>>>(
      q, k, v, gamma, beta, a_h, W_in, W_out, wt_in, wt_out);

  // f = LN(t) @ W_in for all rows; q/k rows pre-normalized per head
  proj_gemm<<<dim3(256), 512, 0, stream>>>(a_h, wt_in, f);

  s_kernel<<<dim3(BH, NSLC), 256, 0, stream>>>(f, S4);

  s_reduce<<<BH, 256, 0, stream>>>(S4, Sh);

  m_build<<<dim3(DIM / 128, BH), 256, 0, stream>>>(wt_out, Sh, Mt);

  // out = g_q @ Mt[b]^T + b_out (per-batch weights)
  fin_gemm<<<dim3(256), 512, 0, stream>>>(f, Mt, b_out, out);
}